// Round 3
// baseline (2131.268 us; speedup 1.0000x reference)
//
#include <hip/hip_runtime.h>
#include <math.h>

#define HID 1024
#define NH 16
#define DH 64
#define SEQ 2048
#define NB 2
#define SPAN 512
#define QT 64
#define KT 64

typedef __attribute__((ext_vector_type(8))) short bf16x8;
typedef __attribute__((ext_vector_type(4))) float f32x4;
typedef __attribute__((ext_vector_type(4))) short short4v;

__device__ __forceinline__ short bf16c(float x) {
  unsigned u = __builtin_bit_cast(unsigned, x);
  unsigned r = (u + 0x7FFFu + ((u >> 16) & 1u)) >> 16;
  return (short)r;
}

// ---------------- bf16-MFMA GEMM: C[M,1024] = (A[M,1024] @ W[1024,1024] + bias) * scale
// A,W fp32 in global; staged to LDS as bf16 (RNE); fp32 accumulate.
// 128x128 tile, BK=32, 4 waves (2x2), each wave 64x64 via 4x4 16x16x32 MFMAs.
__global__ __launch_bounds__(256)
void gemm_bf16(const float* __restrict__ A, const float* __restrict__ W,
               const float* __restrict__ bias, float* __restrict__ C,
               float scale) {
  // padded row stride 40 bf16 (80B): fragment reads land 20 banks apart -> <=2-way
  __shared__ __align__(16) short As[128 * 40];
  __shared__ __align__(16) short Bs[128 * 40];
  const int tid = threadIdx.x;
  const int m0 = blockIdx.y * 128, n0 = blockIdx.x * 128;
  const int w = tid >> 6, l = tid & 63;
  const int wr = w >> 1, wc = w & 1;
  const int lr = l & 15, lh = l >> 4;

  f32x4 acc[4][4];
  #pragma unroll
  for (int m = 0; m < 4; ++m)
    #pragma unroll
    for (int n = 0; n < 4; ++n)
      acc[m][n] = (f32x4){0.f, 0.f, 0.f, 0.f};

  for (int k0 = 0; k0 < HID; k0 += 32) {
    __syncthreads();
    // stage A-tile: 128 rows x 32 k, fp32 -> bf16
    #pragma unroll
    for (int p = 0; p < 4; ++p) {
      int idx = tid + p * 256;           // 0..1023
      int row = idx >> 3, c4 = idx & 7;  // 8 float4 per row
      float4 av = *(const float4*)&A[(size_t)(m0 + row) * HID + k0 + c4 * 4];
      short4v sv;
      sv.x = bf16c(av.x); sv.y = bf16c(av.y);
      sv.z = bf16c(av.z); sv.w = bf16c(av.w);
      *(short4v*)&As[row * 40 + c4 * 4] = sv;
    }
    // stage W-tile transposed: Bs[n][k], 32 k-rows x 128 n-cols
    #pragma unroll
    for (int p = 0; p < 4; ++p) {
      int idx = tid + p * 256;
      int kk = idx >> 5, nn = (idx & 31) * 4;
      float4 wv = *(const float4*)&W[(size_t)(k0 + kk) * HID + n0 + nn];
      Bs[(nn + 0) * 40 + kk] = bf16c(wv.x);
      Bs[(nn + 1) * 40 + kk] = bf16c(wv.y);
      Bs[(nn + 2) * 40 + kk] = bf16c(wv.z);
      Bs[(nn + 3) * 40 + kk] = bf16c(wv.w);
    }
    __syncthreads();

    bf16x8 af[4], bfr[4];
    #pragma unroll
    for (int m = 0; m < 4; ++m)
      af[m] = *(const bf16x8*)&As[(wr * 64 + m * 16 + lr) * 40 + lh * 8];
    #pragma unroll
    for (int n = 0; n < 4; ++n)
      bfr[n] = *(const bf16x8*)&Bs[(wc * 64 + n * 16 + lr) * 40 + lh * 8];
    #pragma unroll
    for (int m = 0; m < 4; ++m)
      #pragma unroll
      for (int n = 0; n < 4; ++n)
        acc[m][n] = __builtin_amdgcn_mfma_f32_16x16x32_bf16(af[m], bfr[n], acc[m][n], 0, 0, 0);
  }

  // epilogue: C/D layout col=lane&15, row=(lane>>4)*4+reg  [m89-verified]
  #pragma unroll
  for (int n = 0; n < 4; ++n) {
    int col = n0 + wc * 64 + n * 16 + lr;
    float bv = bias ? bias[col] : 0.0f;
    #pragma unroll
    for (int m = 0; m < 4; ++m) {
      #pragma unroll
      for (int r = 0; r < 4; ++r) {
        int row = m0 + wr * 64 + m * 16 + lh * 4 + r;
        C[(size_t)row * HID + col] = (acc[m][n][r] + bv) * scale;
      }
    }
  }
}

// XOR swizzle at float4-slot granularity to kill LDS bank conflicts on
// strided-row b128 reads (rows are 64 floats = exactly 2 bank sweeps).
__device__ __forceinline__ int swz(int row, int d4) {
  return d4 ^ ((row >> 2) & 15);
}

// ---------------- fused disentangled attention (flash-style, fp32)
// q is pre-scaled by 1/8; pos_q pre-scaled by 1/(8*sqrt(192)).
// scores[q,k] = q.k + q.pos_k[r] + k.pos_q[r],  r = clip(q-k+512, 0, 1023)
__global__ __launch_bounds__(256)
void attn_fused(const float* __restrict__ qg, const float* __restrict__ kg,
                const float* __restrict__ vg, const float* __restrict__ pkg,
                const float* __restrict__ pqg, float* __restrict__ outg) {
  const int q0 = blockIdx.x * QT;
  const int h  = blockIdx.y;
  const int b  = blockIdx.z;
  const int tid = threadIdx.x;
  const int tx = tid & 15, ty = tid >> 4;

  __shared__ __align__(16) float qs[QT * 64];
  __shared__ __align__(16) float ks[KT * 64];
  __shared__ __align__(16) float vs[KT * 64];
  __shared__ __align__(16) float ps[QT * 64];
  __shared__ __align__(16) float pks[127 * 64];
  __shared__ __align__(16) float pqs[127 * 64];

  // load Q tile (swizzled)
  for (int idx = tid; idx < QT * 16; idx += 256) {
    int i = idx >> 4, d4 = idx & 15;
    *(float4*)&qs[i * 64 + swz(i, d4) * 4] =
        *(const float4*)&qg[((size_t)(b * SEQ + q0 + i)) * HID + h * DH + d4 * 4];
  }

  float m_[4], l_[4], acc[4][4];
  #pragma unroll
  for (int a = 0; a < 4; ++a) {
    m_[a] = -1e30f; l_[a] = 0.0f;
    #pragma unroll
    for (int j = 0; j < 4; ++j) acc[a][j] = 0.0f;
  }

  for (int k0 = 0; k0 < SEQ; k0 += KT) {
    __syncthreads();  // protect LDS (incl. q tile 1st iter, ps/vs from prev PV)
    // stage K and V tiles
    for (int idx = tid; idx < KT * 16; idx += 256) {
      int i = idx >> 4, d4 = idx & 15;
      size_t gb = ((size_t)(b * SEQ + k0 + i)) * HID + h * DH + d4 * 4;
      *(float4*)&ks[i * 64 + swz(i, d4) * 4] = *(const float4*)&kg[gb];
      *(float4*)&vs[i * 64 + swz(i, d4) * 4] = *(const float4*)&vg[gb];
    }
    // stage relative-position rows r_lo..r_hi (<=127 rows)
    int ru_lo = q0 - (k0 + KT - 1) + SPAN;
    int ru_hi = q0 + (QT - 1) - k0 + SPAN;
    int r_lo = min(max(ru_lo, 0), 2 * SPAN - 1);
    int r_hi = min(max(ru_hi, 0), 2 * SPAN - 1);
    int nr = r_hi - r_lo + 1;
    for (int idx = tid; idx < nr * 16; idx += 256) {
      int i = idx >> 4, d4 = idx & 15;
      size_t gb = ((size_t)(r_lo + i)) * HID + h * DH + d4 * 4;
      *(float4*)&pks[i * 64 + swz(i, d4) * 4] = *(const float4*)&pkg[gb];
      *(float4*)&pqs[i * 64 + swz(i, d4) * 4] = *(const float4*)&pqg[gb];
    }
    __syncthreads();

    // ---- scores: 4x4 micro-tile per thread ----
    int rb = (q0 + ty * 4) - (k0 + tx * 4) + SPAN;  // unclipped r at (a=0,b=0)
    int ri7[7];
    #pragma unroll
    for (int i = 0; i < 7; ++i) {
      int r = rb + i - 3;
      r = min(max(r, 0), 2 * SPAN - 1);
      ri7[i] = r - r_lo;
    }
    float sv[4][4] = {};
    #pragma unroll 2
    for (int d4 = 0; d4 < 16; ++d4) {
      float4 qv[4], kv[4], pkv[7], pqv[7];
      #pragma unroll
      for (int a = 0; a < 4; ++a)
        qv[a] = *(const float4*)&qs[(ty * 4 + a) * 64 + swz(ty * 4 + a, d4) * 4];
      #pragma unroll
      for (int bb = 0; bb < 4; ++bb)
        kv[bb] = *(const float4*)&ks[(tx * 4 + bb) * 64 + swz(tx * 4 + bb, d4) * 4];
      #pragma unroll
      for (int i = 0; i < 7; ++i) {
        int r = ri7[i];
        pkv[i] = *(const float4*)&pks[r * 64 + swz(r, d4) * 4];
        pqv[i] = *(const float4*)&pqs[r * 64 + swz(r, d4) * 4];
      }
      #pragma unroll
      for (int a = 0; a < 4; ++a)
        #pragma unroll
        for (int bb = 0; bb < 4; ++bb) {
          int i = a - bb + 3;
          sv[a][bb] += qv[a].x * kv[bb].x + qv[a].y * kv[bb].y +
                       qv[a].z * kv[bb].z + qv[a].w * kv[bb].w +
                       qv[a].x * pkv[i].x + qv[a].y * pkv[i].y +
                       qv[a].z * pkv[i].z + qv[a].w * pkv[i].w +
                       kv[bb].x * pqv[i].x + kv[bb].y * pqv[i].y +
                       kv[bb].z * pqv[i].z + kv[bb].w * pqv[i].w;
        }
    }

    // ---- online softmax (rows ty*4+a; reduce across 16 tx lanes) ----
    #pragma unroll
    for (int a = 0; a < 4; ++a) {
      float mx = fmaxf(fmaxf(sv[a][0], sv[a][1]), fmaxf(sv[a][2], sv[a][3]));
      #pragma unroll
      for (int off = 1; off < 16; off <<= 1)
        mx = fmaxf(mx, __shfl_xor(mx, off, 64));
      float mnew = fmaxf(m_[a], mx);
      float alpha = __expf(m_[a] - mnew);
      int row = ty * 4 + a;
      float s0 = 0.0f;
      #pragma unroll
      for (int bb = 0; bb < 4; ++bb) {
        float p = __expf(sv[a][bb] - mnew);
        int col = tx * 4 + bb;
        ps[row * 64 + swz(row, col >> 2) * 4 + (col & 3)] = p;
        s0 += p;
      }
      #pragma unroll
      for (int off = 1; off < 16; off <<= 1)
        s0 += __shfl_xor(s0, off, 64);
      l_[a] = l_[a] * alpha + s0;
      m_[a] = mnew;
      #pragma unroll
      for (int j = 0; j < 4; ++j) acc[a][j] *= alpha;
    }
    __syncthreads();

    // ---- PV: acc[a][:] += sum_k p[row][k] * v[k][tx*4..] ----
    #pragma unroll 2
    for (int kk = 0; kk < KT; kk += 4) {
      float4 vv[4];
      #pragma unroll
      for (int t = 0; t < 4; ++t)
        vv[t] = *(const float4*)&vs[(kk + t) * 64 + swz(kk + t, tx) * 4];
      #pragma unroll
      for (int a = 0; a < 4; ++a) {
        int row = ty * 4 + a;
        float4 pp = *(const float4*)&ps[row * 64 + swz(row, kk >> 2) * 4];
        acc[a][0] += pp.x * vv[0].x + pp.y * vv[1].x + pp.z * vv[2].x + pp.w * vv[3].x;
        acc[a][1] += pp.x * vv[0].y + pp.y * vv[1].y + pp.z * vv[2].y + pp.w * vv[3].y;
        acc[a][2] += pp.x * vv[0].z + pp.y * vv[1].z + pp.z * vv[2].z + pp.w * vv[3].z;
        acc[a][3] += pp.x * vv[0].w + pp.y * vv[1].w + pp.z * vv[2].w + pp.w * vv[3].w;
      }
    }
  }

  // ---- write output: out[b, s, h*64+d] ----
  #pragma unroll
  for (int a = 0; a < 4; ++a) {
    float inv = 1.0f / l_[a];
    float4 o;
    o.x = acc[a][0] * inv;
    o.y = acc[a][1] * inv;
    o.z = acc[a][2] * inv;
    o.w = acc[a][3] * inv;
    *(float4*)&outg[((size_t)(b * SEQ + q0 + ty * 4 + a)) * HID + h * DH + tx * 4] = o;
  }
}

extern "C" void kernel_launch(void* const* d_in, const int* in_sizes, int n_in,
                              void* d_out, int out_size, void* d_ws, size_t ws_size,
                              hipStream_t stream) {
  const float* hs  = (const float*)d_in[0];
  const float* rel = (const float*)d_in[1];
  const float* Wq  = (const float*)d_in[2];
  const float* bq  = (const float*)d_in[3];
  const float* Wk  = (const float*)d_in[4];
  const float* bk  = (const float*)d_in[5];
  const float* Wv  = (const float*)d_in[6];
  const float* bv  = (const float*)d_in[7];
  const float* Wpk = (const float*)d_in[8];
  const float* Wpq = (const float*)d_in[9];
  const float* bpq = (const float*)d_in[10];
  float* out = (float*)d_out;

  float* ws = (float*)d_ws;
  float* q  = ws;                       // 4096*1024
  float* k  = ws + 4194304;
  float* v  = ws + 8388608;
  float* pk = ws + 12582912;            // 1024*1024
  float* pq = ws + 13631488;

  const float qscale  = 0.125f;                          // 1/sqrt(64)
  const float pqscale = 1.0f / (8.0f * sqrtf(192.0f));   // 1/(sqrt(64)*sqrt(64*3))

  dim3 blk(256);
  dim3 gp(HID / 128, (NB * SEQ) / 128);                  // 8 x 32
  gemm_bf16<<<gp, blk, 0, stream>>>(hs, Wq, bq, q, qscale);
  gemm_bf16<<<gp, blk, 0, stream>>>(hs, Wk, bk, k, 1.0f);
  gemm_bf16<<<gp, blk, 0, stream>>>(hs, Wv, bv, v, 1.0f);

  dim3 gp2(HID / 128, (2 * SPAN) / 128);                 // 8 x 8
  gemm_bf16<<<gp2, blk, 0, stream>>>(rel, Wpk, nullptr, pk, 1.0f);
  gemm_bf16<<<gp2, blk, 0, stream>>>(rel, Wpq, bpq, pq, pqscale);

  dim3 ga(SEQ / QT, NH, NB);
  attn_fused<<<ga, blk, 0, stream>>>(q, k, v, pk, pq, out);
}

// Round 5
// 730.473 us; speedup vs baseline: 2.9177x; 2.9177x over previous
//
#include <hip/hip_runtime.h>
#include <math.h>

#define HID 1024
#define NH 16
#define DH 64
#define SEQ 2048
#define NB 2
#define SPAN 512
#define PSTR 72    // padded f16 row stride (144 B: stride-144 b128 frag reads <=2-way)
#define BSTR 136   // band row stride (128 cols + pad)

typedef __attribute__((ext_vector_type(8))) _Float16 f16x8;
typedef __attribute__((ext_vector_type(4))) _Float16 f16x4;
typedef __attribute__((ext_vector_type(4))) float f32x4;

// ---------------- f16-MFMA GEMM: C[M,1024] = f16((A @ W + bias) * scale)
// 128x128 tile, BK=32, 4 waves (2x2), each wave 64x64 via 4x4 16x16x32 MFMAs.
__global__ __launch_bounds__(256)
void gemm_f16(const float* __restrict__ A, const float* __restrict__ W,
              const float* __restrict__ bias, _Float16* __restrict__ C,
              float scale) {
  __shared__ _Float16 As[128 * 40];
  __shared__ _Float16 Bs[128 * 40];
  const int tid = threadIdx.x;
  const int m0 = blockIdx.y * 128, n0 = blockIdx.x * 128;
  const int w = tid >> 6, l = tid & 63;
  const int wr = w >> 1, wc = w & 1;
  const int lr = l & 15, lh = l >> 4;

  f32x4 acc[4][4];
  #pragma unroll
  for (int m = 0; m < 4; ++m)
    #pragma unroll
    for (int n = 0; n < 4; ++n)
      acc[m][n] = (f32x4){0.f, 0.f, 0.f, 0.f};

  for (int k0 = 0; k0 < HID; k0 += 32) {
    __syncthreads();
    #pragma unroll
    for (int p = 0; p < 4; ++p) {
      int idx = tid + p * 256;
      int row = idx >> 3, c4 = idx & 7;
      float4 av = *(const float4*)&A[(size_t)(m0 + row) * HID + k0 + c4 * 4];
      f16x4 sv;
      sv.x = (_Float16)av.x; sv.y = (_Float16)av.y;
      sv.z = (_Float16)av.z; sv.w = (_Float16)av.w;
      *(f16x4*)&As[row * 40 + c4 * 4] = sv;
    }
    #pragma unroll
    for (int p = 0; p < 4; ++p) {
      int idx = tid + p * 256;
      int kk = idx >> 5, nn = (idx & 31) * 4;
      float4 wv = *(const float4*)&W[(size_t)(k0 + kk) * HID + n0 + nn];
      Bs[(nn + 0) * 40 + kk] = (_Float16)wv.x;
      Bs[(nn + 1) * 40 + kk] = (_Float16)wv.y;
      Bs[(nn + 2) * 40 + kk] = (_Float16)wv.z;
      Bs[(nn + 3) * 40 + kk] = (_Float16)wv.w;
    }
    __syncthreads();

    f16x8 af[4], bfr[4];
    #pragma unroll
    for (int m = 0; m < 4; ++m)
      af[m] = *(const f16x8*)&As[(wr * 64 + m * 16 + lr) * 40 + lh * 8];
    #pragma unroll
    for (int n = 0; n < 4; ++n)
      bfr[n] = *(const f16x8*)&Bs[(wc * 64 + n * 16 + lr) * 40 + lh * 8];
    #pragma unroll
    for (int m = 0; m < 4; ++m)
      #pragma unroll
      for (int n = 0; n < 4; ++n)
        acc[m][n] = __builtin_amdgcn_mfma_f32_16x16x32_f16(af[m], bfr[n], acc[m][n], 0, 0, 0);
  }

  #pragma unroll
  for (int n = 0; n < 4; ++n) {
    int col = n0 + wc * 64 + n * 16 + lr;
    float bv = bias ? bias[col] : 0.0f;
    #pragma unroll
    for (int m = 0; m < 4; ++m)
      #pragma unroll
      for (int r = 0; r < 4; ++r) {
        int row = m0 + wr * 64 + m * 16 + lh * 4 + r;
        C[(size_t)row * HID + col] = (_Float16)((acc[m][n][r] + bv) * scale);
      }
  }
}

// ---------------- fused disentangled attention, f16 MFMA, fp32 softmax
// scores[q,k] = q.k + q.pos_k[r] + k.pos_q[r],  r = clip(q-k+512, 0, 1023)
// (q pre-scaled 1/8; pos_q pre-scaled 1/(8*sqrt(192)))
// 4 waves, each owns 16 q-rows and the FULL 64-col score row.
__global__ __launch_bounds__(256, 2)
void attn_mfma(const _Float16* __restrict__ qg, const _Float16* __restrict__ kg,
               const _Float16* __restrict__ vg, const _Float16* __restrict__ pkg,
               const _Float16* __restrict__ pqg, float* __restrict__ outg) {
  const int q0 = blockIdx.x * 64;
  const int h = blockIdx.y, b = blockIdx.z;
  const int tid = threadIdx.x;
  const int w = tid >> 6, l = tid & 63;
  const int lr = l & 15, lh = l >> 4;
  const size_t hoff = (size_t)h * DH;

  __shared__ _Float16 qs[64 * PSTR];
  __shared__ _Float16 ks[64 * PSTR];
  __shared__ _Float16 vst[64 * PSTR];   // V^T: vst[d][ki]
  __shared__ _Float16 ps[64 * PSTR];    // P tile
  __shared__ _Float16 posA[128 * PSTR]; // pos_k rows; aliased by c2p band [64][BSTR]
  __shared__ _Float16 posB[128 * PSTR]; // pos_q rows; aliased by p2c band
  _Float16* c2pb = posA;
  _Float16* p2cb = posB;

  // stage Q once (first loop-top sync covers it)
  for (int idx = tid; idx < 64 * 8; idx += 256) {
    int row = idx >> 3, c = idx & 7;
    *(f16x8*)&qs[row * PSTR + c * 8] =
        *(const f16x8*)&qg[((size_t)(b * SEQ + q0 + row)) * HID + hoff + c * 8];
  }

  f32x4 accO[4];
  float m_[4], l_[4];
  #pragma unroll
  for (int r = 0; r < 4; ++r) { m_[r] = -1e30f; l_[r] = 0.0f; }
  #pragma unroll
  for (int nt = 0; nt < 4; ++nt) accO[nt] = (f32x4){0.f, 0.f, 0.f, 0.f};

  for (int k0 = 0; k0 < SEQ; k0 += 64) {
    __syncthreads();
    // ---- stage K, V^T, pos rows ----
    for (int idx = tid; idx < 64 * 8; idx += 256) {
      int row = idx >> 3, c = idx & 7;
      *(f16x8*)&ks[row * PSTR + c * 8] =
          *(const f16x8*)&kg[((size_t)(b * SEQ + k0 + row)) * HID + hoff + c * 8];
    }
    for (int idx = tid; idx < 64 * 8; idx += 256) {
      int row = idx >> 3, c = idx & 7;
      f16x8 vv = *(const f16x8*)&vg[((size_t)(b * SEQ + k0 + row)) * HID + hoff + c * 8];
      #pragma unroll
      for (int jj = 0; jj < 8; ++jj) {
        int j = (jj + c) & 7;                      // rotated order; identity mapping
        vst[(c * 8 + j) * PSTR + row] = vv[j];     // vst[d][ki] = V[ki][d]
      }
    }
    const int r_lo = min(max(q0 - k0 - 63 + SPAN, 0), 2 * SPAN - 1);
    const int r_hi = min(max(q0 - k0 + 63 + SPAN, 0), 2 * SPAN - 1);
    const int nr = r_hi - r_lo + 1;
    for (int idx = tid; idx < nr * 8; idx += 256) {
      int row = idx >> 3, c = idx & 7;
      size_t gb = ((size_t)(r_lo + row)) * HID + hoff + c * 8;
      *(f16x8*)&posA[row * PSTR + c * 8] = *(const f16x8*)&pkg[gb];
      *(f16x8*)&posB[row * PSTR + c * 8] = *(const f16x8*)&pqg[gb];
    }
    __syncthreads();

    // ---- MFMA phase ----
    f16x8 aq[2], ak[2];
    #pragma unroll
    for (int kk = 0; kk < 2; ++kk) {
      aq[kk] = *(const f16x8*)&qs[(w * 16 + lr) * PSTR + kk * 32 + lh * 8];
      ak[kk] = *(const f16x8*)&ks[(w * 16 + lr) * PSTR + kk * 32 + lh * 8];
    }

    // QK^T: full 64 cols for this wave's 16 q-rows
    f32x4 sqk[4];
    #pragma unroll
    for (int nt = 0; nt < 4; ++nt) sqk[nt] = (f32x4){0.f, 0.f, 0.f, 0.f};
    #pragma unroll
    for (int nt = 0; nt < 4; ++nt)
      #pragma unroll
      for (int kk = 0; kk < 2; ++kk) {
        f16x8 bk = *(const f16x8*)&ks[(nt * 16 + lr) * PSTR + kk * 32 + lh * 8];
        sqk[nt] = __builtin_amdgcn_mfma_f32_16x16x32_f16(aq[kk], bk, sqk[nt], 0, 0, 0);
      }

    // c2p band: q-rows x 128 r-cols
    f32x4 bandA[8];
    #pragma unroll
    for (int nt = 0; nt < 8; ++nt) bandA[nt] = (f32x4){0.f, 0.f, 0.f, 0.f};
    #pragma unroll
    for (int nt = 0; nt < 8; ++nt)
      #pragma unroll
      for (int kk = 0; kk < 2; ++kk) {
        f16x8 bp = *(const f16x8*)&posA[(nt * 16 + lr) * PSTR + kk * 32 + lh * 8];
        bandA[nt] = __builtin_amdgcn_mfma_f32_16x16x32_f16(aq[kk], bp, bandA[nt], 0, 0, 0);
      }

    // p2c band: k-rows x 128 r-cols
    f32x4 bandB[8];
    #pragma unroll
    for (int nt = 0; nt < 8; ++nt) bandB[nt] = (f32x4){0.f, 0.f, 0.f, 0.f};
    #pragma unroll
    for (int nt = 0; nt < 8; ++nt)
      #pragma unroll
      for (int kk = 0; kk < 2; ++kk) {
        f16x8 bp = *(const f16x8*)&posB[(nt * 16 + lr) * PSTR + kk * 32 + lh * 8];
        bandB[nt] = __builtin_amdgcn_mfma_f32_16x16x32_f16(ak[kk], bp, bandB[nt], 0, 0, 0);
      }
    __syncthreads();  // all reads of posA/posB complete

    // ---- write bands into pos LDS space (aliased) ----
    #pragma unroll
    for (int nt = 0; nt < 8; ++nt)
      #pragma unroll
      for (int r = 0; r < 4; ++r) {
        int rowi = w * 16 + lh * 4 + r;
        int col = nt * 16 + lr;
        c2pb[rowi * BSTR + col] = (_Float16)bandA[nt][r];
        p2cb[rowi * BSTR + col] = (_Float16)bandB[nt][r];
      }
    __syncthreads();

    // ---- assemble scores, online softmax (full row per wave), write P ----
    const int rbase = q0 - k0 + SPAN;
    #pragma unroll
    for (int r = 0; r < 4; ++r) {
      int qi = w * 16 + lh * 4 + r;
      float sc[4];
      #pragma unroll
      for (int nt = 0; nt < 4; ++nt) {
        int ki = nt * 16 + lr;
        int rr = min(max(rbase + qi - ki, 0), 2 * SPAN - 1);
        int ri = rr - r_lo;
        sc[nt] = sqk[nt][r] + (float)c2pb[qi * BSTR + ri] + (float)p2cb[ki * BSTR + ri];
      }
      float mx = fmaxf(fmaxf(sc[0], sc[1]), fmaxf(sc[2], sc[3]));
      #pragma unroll
      for (int off = 1; off < 16; off <<= 1)
        mx = fmaxf(mx, __shfl_xor(mx, off, 64));
      float mnew = fmaxf(m_[r], mx);
      float alpha = __expf(m_[r] - mnew);
      float s0 = 0.0f;
      #pragma unroll
      for (int nt = 0; nt < 4; ++nt) {
        float p = __expf(sc[nt] - mnew);
        s0 += p;
        ps[qi * PSTR + nt * 16 + lr] = (_Float16)p;
      }
      #pragma unroll
      for (int off = 1; off < 16; off <<= 1)
        s0 += __shfl_xor(s0, off, 64);
      l_[r] = l_[r] * alpha + s0;
      m_[r] = mnew;
      #pragma unroll
      for (int nt = 0; nt < 4; ++nt) accO[nt][r] *= alpha;
    }
    __syncthreads();

    // ---- PV: O[16 q-rows][64 d] += P[16][64] @ V[64][64] ----
    f16x8 pa[2];
    #pragma unroll
    for (int kk = 0; kk < 2; ++kk)
      pa[kk] = *(const f16x8*)&ps[(w * 16 + lr) * PSTR + kk * 32 + lh * 8];
    #pragma unroll
    for (int nt = 0; nt < 4; ++nt)
      #pragma unroll
      for (int kk = 0; kk < 2; ++kk) {
        f16x8 vb = *(const f16x8*)&vst[(nt * 16 + lr) * PSTR + kk * 32 + lh * 8];
        accO[nt] = __builtin_amdgcn_mfma_f32_16x16x32_f16(pa[kk], vb, accO[nt], 0, 0, 0);
      }
  }

  // ---- output ----
  #pragma unroll
  for (int r = 0; r < 4; ++r) {
    float inv = 1.0f / l_[r];
    int row = q0 + w * 16 + lh * 4 + r;
    #pragma unroll
    for (int nt = 0; nt < 4; ++nt) {
      int col = h * DH + nt * 16 + lr;
      outg[((size_t)(b * SEQ + row)) * HID + col] = accO[nt][r] * inv;
    }
  }
}

extern "C" void kernel_launch(void* const* d_in, const int* in_sizes, int n_in,
                              void* d_out, int out_size, void* d_ws, size_t ws_size,
                              hipStream_t stream) {
  const float* hs  = (const float*)d_in[0];
  const float* rel = (const float*)d_in[1];
  const float* Wq  = (const float*)d_in[2];
  const float* bq  = (const float*)d_in[3];
  const float* Wk  = (const float*)d_in[4];
  const float* bk  = (const float*)d_in[5];
  const float* Wv  = (const float*)d_in[6];
  const float* bv  = (const float*)d_in[7];
  const float* Wpk = (const float*)d_in[8];
  const float* Wpq = (const float*)d_in[9];
  const float* bpq = (const float*)d_in[10];
  float* out = (float*)d_out;

  _Float16* ws = (_Float16*)d_ws;
  _Float16* q  = ws;                    // 4096*1024 f16
  _Float16* k  = ws + 4194304;
  _Float16* v  = ws + 8388608;
  _Float16* pk = ws + 12582912;         // 1024*1024 f16
  _Float16* pq = ws + 13631488;

  const float qscale  = 0.125f;                          // 1/sqrt(64)
  const float pqscale = 1.0f / (8.0f * sqrtf(192.0f));   // 1/(sqrt(64)*sqrt(64*3))

  dim3 blk(256);
  dim3 gp(HID / 128, (NB * SEQ) / 128);                  // 8 x 32
  gemm_f16<<<gp, blk, 0, stream>>>(hs, Wq, bq, q, qscale);
  gemm_f16<<<gp, blk, 0, stream>>>(hs, Wk, bk, k, 1.0f);
  gemm_f16<<<gp, blk, 0, stream>>>(hs, Wv, bv, v, 1.0f);

  dim3 gp2(HID / 128, (2 * SPAN) / 128);                 // 8 x 8
  gemm_f16<<<gp2, blk, 0, stream>>>(rel, Wpk, nullptr, pk, 1.0f);
  gemm_f16<<<gp2, blk, 0, stream>>>(rel, Wpq, bpq, pq, pqscale);

  dim3 ga(SEQ / 64, NH, NB);
  attn_mfma<<<ga, blk, 0, stream>>>(q, k, v, pk, pq, out);
}

// Round 6
// 687.709 us; speedup vs baseline: 3.0991x; 1.0622x over previous
//
#include <hip/hip_runtime.h>
#include <math.h>

#define HID 1024
#define NH 16
#define DH 64
#define SEQ 2048
#define NB 2
#define SPAN 512
#define PSTR 72    // padded f16 row stride (144 B: stride-144 b128 frag reads <=2-way)

typedef __attribute__((ext_vector_type(8))) _Float16 f16x8;
typedef __attribute__((ext_vector_type(4))) _Float16 f16x4;
typedef __attribute__((ext_vector_type(4))) float f32x4;

// ---------------- f16-MFMA GEMM: C[M,1024] = f16((A @ W + bias) * scale)
// 128x128 tile, BK=32, 4 waves (2x2), each wave 64x64 via 4x4 16x16x32 MFMAs.
__global__ __launch_bounds__(256)
void gemm_f16(const float* __restrict__ A, const float* __restrict__ W,
              const float* __restrict__ bias, _Float16* __restrict__ C,
              float scale) {
  __shared__ _Float16 As[128 * 40];
  __shared__ _Float16 Bs[128 * 40];
  const int tid = threadIdx.x;
  const int m0 = blockIdx.y * 128, n0 = blockIdx.x * 128;
  const int w = tid >> 6, l = tid & 63;
  const int wr = w >> 1, wc = w & 1;
  const int lr = l & 15, lh = l >> 4;

  f32x4 acc[4][4];
  #pragma unroll
  for (int m = 0; m < 4; ++m)
    #pragma unroll
    for (int n = 0; n < 4; ++n)
      acc[m][n] = (f32x4){0.f, 0.f, 0.f, 0.f};

  for (int k0 = 0; k0 < HID; k0 += 32) {
    __syncthreads();
    #pragma unroll
    for (int p = 0; p < 4; ++p) {
      int idx = tid + p * 256;
      int row = idx >> 3, c4 = idx & 7;
      float4 av = *(const float4*)&A[(size_t)(m0 + row) * HID + k0 + c4 * 4];
      f16x4 sv;
      sv.x = (_Float16)av.x; sv.y = (_Float16)av.y;
      sv.z = (_Float16)av.z; sv.w = (_Float16)av.w;
      *(f16x4*)&As[row * 40 + c4 * 4] = sv;
    }
    #pragma unroll
    for (int p = 0; p < 4; ++p) {
      int idx = tid + p * 256;
      int kk = idx >> 5, nn = (idx & 31) * 4;
      float4 wv = *(const float4*)&W[(size_t)(k0 + kk) * HID + n0 + nn];
      Bs[(nn + 0) * 40 + kk] = (_Float16)wv.x;
      Bs[(nn + 1) * 40 + kk] = (_Float16)wv.y;
      Bs[(nn + 2) * 40 + kk] = (_Float16)wv.z;
      Bs[(nn + 3) * 40 + kk] = (_Float16)wv.w;
    }
    __syncthreads();

    f16x8 af[4], bfr[4];
    #pragma unroll
    for (int m = 0; m < 4; ++m)
      af[m] = *(const f16x8*)&As[(wr * 64 + m * 16 + lr) * 40 + lh * 8];
    #pragma unroll
    for (int n = 0; n < 4; ++n)
      bfr[n] = *(const f16x8*)&Bs[(wc * 64 + n * 16 + lr) * 40 + lh * 8];
    #pragma unroll
    for (int m = 0; m < 4; ++m)
      #pragma unroll
      for (int n = 0; n < 4; ++n)
        acc[m][n] = __builtin_amdgcn_mfma_f32_16x16x32_f16(af[m], bfr[n], acc[m][n], 0, 0, 0);
  }

  #pragma unroll
  for (int n = 0; n < 4; ++n) {
    int col = n0 + wc * 64 + n * 16 + lr;
    float bv = bias ? bias[col] : 0.0f;
    #pragma unroll
    for (int m = 0; m < 4; ++m)
      #pragma unroll
      for (int r = 0; r < 4; ++r) {
        int row = m0 + wr * 64 + m * 16 + lh * 4 + r;
        C[(size_t)row * HID + col] = (_Float16)((acc[m][n][r] + bv) * scale);
      }
  }
}

// ---------------- fused disentangled attention, f16 MFMA, fp32 softmax
// scores[q,k] = q.k + q.pos_k[rr] + k.pos_q[rr],  rr = clip(q-k+512, 0, 1023)
// (q pre-scaled 1/8; pos_q pre-scaled 1/(8*sqrt(192)))
// 4 waves, each owns 16 q-rows and the FULL 64-col score row.
// Bands computed by MFMA into [qi][ri]/[ki][ri], stored TRANSPOSED ([ri][*],
// stride 72) with f16x4 writes; only ceil(nr/16) band tiles computed (clip).
__global__ __launch_bounds__(256, 2)
void attn_mfma(const _Float16* __restrict__ qg, const _Float16* __restrict__ kg,
               const _Float16* __restrict__ vg, const _Float16* __restrict__ pkg,
               const _Float16* __restrict__ pqg, float* __restrict__ outg) {
  const int q0 = blockIdx.x * 64;
  const int h = blockIdx.y, b = blockIdx.z;
  const int tid = threadIdx.x;
  const int w = tid >> 6, l = tid & 63;
  const int lr = l & 15, lh = l >> 4;
  const size_t hoff = (size_t)h * DH;

  __shared__ _Float16 qs[64 * PSTR];
  __shared__ _Float16 ks[64 * PSTR];
  __shared__ _Float16 vst[64 * PSTR];   // V^T: vst[d][ki]
  __shared__ _Float16 ps[64 * PSTR];    // P tile (qi-major)
  __shared__ _Float16 posA[128 * PSTR]; // pos_k rows; aliased by c2pT[ri][qi]
  __shared__ _Float16 posB[128 * PSTR]; // pos_q rows; aliased by p2cT[ri][ki]
  _Float16* c2pT = posA;
  _Float16* p2cT = posB;

  // stage Q once (first loop-top sync covers it)
  for (int idx = tid; idx < 64 * 8; idx += 256) {
    int row = idx >> 3, c = idx & 7;
    *(f16x8*)&qs[row * PSTR + c * 8] =
        *(const f16x8*)&qg[((size_t)(b * SEQ + q0 + row)) * HID + hoff + c * 8];
  }

  f32x4 accO[4];
  float m_[4], l_[4];
  #pragma unroll
  for (int r = 0; r < 4; ++r) { m_[r] = -1e30f; l_[r] = 0.0f; }
  #pragma unroll
  for (int nt = 0; nt < 4; ++nt) accO[nt] = (f32x4){0.f, 0.f, 0.f, 0.f};

  for (int k0 = 0; k0 < SEQ; k0 += 64) {
    __syncthreads();
    // ---- stage K, V^T, pos rows ----
    for (int idx = tid; idx < 64 * 8; idx += 256) {
      int row = idx >> 3, c = idx & 7;
      *(f16x8*)&ks[row * PSTR + c * 8] =
          *(const f16x8*)&kg[((size_t)(b * SEQ + k0 + row)) * HID + hoff + c * 8];
    }
    for (int idx = tid; idx < 64 * 8; idx += 256) {
      int row = idx >> 3, c = idx & 7;
      f16x8 vv = *(const f16x8*)&vg[((size_t)(b * SEQ + k0 + row)) * HID + hoff + c * 8];
      #pragma unroll
      for (int jj = 0; jj < 8; ++jj) {
        int j = (jj + c) & 7;                      // rotated order (bank spread)
        vst[(c * 8 + j) * PSTR + row] = vv[j];     // vst[d][ki] = V[ki][d]
      }
    }
    const int r_lo = min(max(q0 - k0 - 63 + SPAN, 0), 2 * SPAN - 1);
    const int r_hi = min(max(q0 - k0 + 63 + SPAN, 0), 2 * SPAN - 1);
    const int nr = r_hi - r_lo + 1;
    const int bt_lim = (nr + 15) >> 4;             // band tiles actually needed
    for (int idx = tid; idx < nr * 8; idx += 256) {
      int row = idx >> 3, c = idx & 7;
      size_t gb = ((size_t)(r_lo + row)) * HID + hoff + c * 8;
      *(f16x8*)&posA[row * PSTR + c * 8] = *(const f16x8*)&pkg[gb];
      *(f16x8*)&posB[row * PSTR + c * 8] = *(const f16x8*)&pqg[gb];
    }
    __syncthreads();

    // ---- MFMA phase ----
    f16x8 aq[2], ak[2];
    #pragma unroll
    for (int kk = 0; kk < 2; ++kk) {
      aq[kk] = *(const f16x8*)&qs[(w * 16 + lr) * PSTR + kk * 32 + lh * 8];
      ak[kk] = *(const f16x8*)&ks[(w * 16 + lr) * PSTR + kk * 32 + lh * 8];
    }

    // QK^T: full 64 cols for this wave's 16 q-rows
    f32x4 sqk[4];
    #pragma unroll
    for (int nt = 0; nt < 4; ++nt) sqk[nt] = (f32x4){0.f, 0.f, 0.f, 0.f};
    #pragma unroll
    for (int nt = 0; nt < 4; ++nt)
      #pragma unroll
      for (int kk = 0; kk < 2; ++kk) {
        f16x8 bk = *(const f16x8*)&ks[(nt * 16 + lr) * PSTR + kk * 32 + lh * 8];
        sqk[nt] = __builtin_amdgcn_mfma_f32_16x16x32_f16(aq[kk], bk, sqk[nt], 0, 0, 0);
      }

    // c2p band: [16 q-rows][bt_lim*16 r-cols]   (bt >= bt_lim clipped away)
    f32x4 bandA[8], bandB[8];
    #pragma unroll
    for (int bt = 0; bt < 8; ++bt) {
      bandA[bt] = (f32x4){0.f, 0.f, 0.f, 0.f};
      bandB[bt] = (f32x4){0.f, 0.f, 0.f, 0.f};
    }
    #pragma unroll
    for (int bt = 0; bt < 8; ++bt)
      if (bt < bt_lim)
        #pragma unroll
        for (int kk = 0; kk < 2; ++kk) {
          f16x8 bp = *(const f16x8*)&posA[(bt * 16 + lr) * PSTR + kk * 32 + lh * 8];
          bandA[bt] = __builtin_amdgcn_mfma_f32_16x16x32_f16(aq[kk], bp, bandA[bt], 0, 0, 0);
        }
    // p2c band: [16 k-rows][bt_lim*16 r-cols]
    #pragma unroll
    for (int bt = 0; bt < 8; ++bt)
      if (bt < bt_lim)
        #pragma unroll
        for (int kk = 0; kk < 2; ++kk) {
          f16x8 bp = *(const f16x8*)&posB[(bt * 16 + lr) * PSTR + kk * 32 + lh * 8];
          bandB[bt] = __builtin_amdgcn_mfma_f32_16x16x32_f16(ak[kk], bp, bandB[bt], 0, 0, 0);
        }
    __syncthreads();  // all reads of posA/posB complete

    // ---- write bands TRANSPOSED into pos LDS space (f16x4 vector writes) ----
    // bandX[bt] lane(lr,lh) reg r = (row_i = w*16+lh*4+r, ri = bt*16+lr)
    #pragma unroll
    for (int bt = 0; bt < 8; ++bt)
      if (bt < bt_lim) {
        f16x4 wa, wb;
        #pragma unroll
        for (int r = 0; r < 4; ++r) {
          wa[r] = (_Float16)bandA[bt][r];
          wb[r] = (_Float16)bandB[bt][r];
        }
        *(f16x4*)&c2pT[(bt * 16 + lr) * PSTR + w * 16 + lh * 4] = wa;
        *(f16x4*)&p2cT[(bt * 16 + lr) * PSTR + w * 16 + lh * 4] = wb;
      }
    __syncthreads();

    // ---- assemble scores, online softmax (full row per wave), write P ----
    const int rbase = q0 - k0 + SPAN;
    #pragma unroll
    for (int r = 0; r < 4; ++r) {
      int qi = w * 16 + lh * 4 + r;
      float sc[4];
      #pragma unroll
      for (int nt = 0; nt < 4; ++nt) {
        int ki = nt * 16 + lr;
        int rr = min(max(rbase + qi - ki, 0), 2 * SPAN - 1);
        int ri = rr - r_lo;
        sc[nt] = sqk[nt][r] + (float)c2pT[ri * PSTR + qi] + (float)p2cT[ri * PSTR + ki];
      }
      float mx = fmaxf(fmaxf(sc[0], sc[1]), fmaxf(sc[2], sc[3]));
      #pragma unroll
      for (int off = 1; off < 16; off <<= 1)
        mx = fmaxf(mx, __shfl_xor(mx, off, 64));
      float mnew = fmaxf(m_[r], mx);
      float alpha = __expf(m_[r] - mnew);
      float s0 = 0.0f;
      #pragma unroll
      for (int nt = 0; nt < 4; ++nt) {
        float p = __expf(sc[nt] - mnew);
        s0 += p;
        ps[qi * PSTR + nt * 16 + lr] = (_Float16)p;
      }
      #pragma unroll
      for (int off = 1; off < 16; off <<= 1)
        s0 += __shfl_xor(s0, off, 64);
      l_[r] = l_[r] * alpha + s0;
      m_[r] = mnew;
      #pragma unroll
      for (int nt = 0; nt < 4; ++nt) accO[nt][r] *= alpha;
    }
    __syncthreads();

    // ---- PV: O[16 q-rows][64 d] += P[16][64] @ V[64][64] ----
    f16x8 pa[2];
    #pragma unroll
    for (int kk = 0; kk < 2; ++kk)
      pa[kk] = *(const f16x8*)&ps[(w * 16 + lr) * PSTR + kk * 32 + lh * 8];
    #pragma unroll
    for (int nt = 0; nt < 4; ++nt)
      #pragma unroll
      for (int kk = 0; kk < 2; ++kk) {
        f16x8 vb = *(const f16x8*)&vst[(nt * 16 + lr) * PSTR + kk * 32 + lh * 8];
        accO[nt] = __builtin_amdgcn_mfma_f32_16x16x32_f16(pa[kk], vb, accO[nt], 0, 0, 0);
      }
  }

  // ---- output ----
  #pragma unroll
  for (int r = 0; r < 4; ++r) {
    float inv = 1.0f / l_[r];
    int row = q0 + w * 16 + lh * 4 + r;
    #pragma unroll
    for (int nt = 0; nt < 4; ++nt) {
      int col = h * DH + nt * 16 + lr;
      outg[((size_t)(b * SEQ + row)) * HID + col] = accO[nt][r] * inv;
    }
  }
}

extern "C" void kernel_launch(void* const* d_in, const int* in_sizes, int n_in,
                              void* d_out, int out_size, void* d_ws, size_t ws_size,
                              hipStream_t stream) {
  const float* hs  = (const float*)d_in[0];
  const float* rel = (const float*)d_in[1];
  const float* Wq  = (const float*)d_in[2];
  const float* bq  = (const float*)d_in[3];
  const float* Wk  = (const float*)d_in[4];
  const float* bk  = (const float*)d_in[5];
  const float* Wv  = (const float*)d_in[6];
  const float* bv  = (const float*)d_in[7];
  const float* Wpk = (const float*)d_in[8];
  const float* Wpq = (const float*)d_in[9];
  const float* bpq = (const float*)d_in[10];
  float* out = (float*)d_out;

  _Float16* ws = (_Float16*)d_ws;
  _Float16* q  = ws;                    // 4096*1024 f16
  _Float16* k  = ws + 4194304;
  _Float16* v  = ws + 8388608;
  _Float16* pk = ws + 12582912;         // 1024*1024 f16
  _Float16* pq = ws + 13631488;

  const float qscale  = 0.125f;                          // 1/sqrt(64)
  const float pqscale = 1.0f / (8.0f * sqrtf(192.0f));   // 1/(sqrt(64)*sqrt(64*3))

  dim3 blk(256);
  dim3 gp(HID / 128, (NB * SEQ) / 128);                  // 8 x 32
  gemm_f16<<<gp, blk, 0, stream>>>(hs, Wq, bq, q, qscale);
  gemm_f16<<<gp, blk, 0, stream>>>(hs, Wk, bk, k, 1.0f);
  gemm_f16<<<gp, blk, 0, stream>>>(hs, Wv, bv, v, 1.0f);

  dim3 gp2(HID / 128, (2 * SPAN) / 128);                 // 8 x 8
  gemm_f16<<<gp2, blk, 0, stream>>>(rel, Wpk, nullptr, pk, 1.0f);
  gemm_f16<<<gp2, blk, 0, stream>>>(rel, Wpq, bpq, pq, pqscale);

  dim3 ga(SEQ / 64, NH, NB);
  attn_mfma<<<ga, blk, 0, stream>>>(q, k, v, pk, pq, out);
}

// Round 7
// 445.872 us; speedup vs baseline: 4.7800x; 1.5424x over previous
//
#include <hip/hip_runtime.h>
#include <math.h>

#define HID 1024
#define NH 16
#define DH 64
#define SEQ 2048
#define NB 2
#define SPAN 512
#define PSTR 72    // padded f16 row stride (144 B: stride-144 b128 frag reads <=2-way)

typedef __attribute__((ext_vector_type(8))) _Float16 f16x8;
typedef __attribute__((ext_vector_type(4))) _Float16 f16x4;
typedef __attribute__((ext_vector_type(4))) float f32x4;

// ---------------- f32 -> f16 convert (n4 = n/4)
__global__ __launch_bounds__(256)
void cvt16(const float* __restrict__ src, _Float16* __restrict__ dst, int n4) {
  int i = blockIdx.x * 256 + threadIdx.x;
  const int stride = gridDim.x * 256;
  for (; i < n4; i += stride) {
    float4 v = ((const float4*)src)[i];
    f16x4 o;
    o.x = (_Float16)v.x; o.y = (_Float16)v.y;
    o.z = (_Float16)v.z; o.w = (_Float16)v.w;
    ((f16x4*)dst)[i] = o;
  }
}

// ---------------- transpose+convert: Wt[z][n][k] = (f16) W_z[k][n]
__global__ __launch_bounds__(256)
void transW(const float* __restrict__ W0, const float* __restrict__ W1,
            const float* __restrict__ W2, const float* __restrict__ W3,
            const float* __restrict__ W4, _Float16* __restrict__ Wt) {
  const int z = blockIdx.z;
  const float* W = z == 0 ? W0 : z == 1 ? W1 : z == 2 ? W2 : z == 3 ? W3 : W4;
  _Float16* out = Wt + (size_t)z * HID * HID;
  const int k0 = blockIdx.x * 64, n0 = blockIdx.y * 64;
  __shared__ _Float16 t[64][72];
  const int tid = threadIdx.x;
  #pragma unroll
  for (int p = 0; p < 4; ++p) {
    int idx = tid + p * 256;          // 0..1023 over 64 rows x 16 float4
    int row = idx >> 4, c4 = idx & 15;
    float4 v = *(const float4*)&W[(size_t)(k0 + row) * HID + n0 + c4 * 4];
    t[c4 * 4 + 0][row] = (_Float16)v.x;
    t[c4 * 4 + 1][row] = (_Float16)v.y;
    t[c4 * 4 + 2][row] = (_Float16)v.z;
    t[c4 * 4 + 3][row] = (_Float16)v.w;
  }
  __syncthreads();
  #pragma unroll
  for (int p = 0; p < 2; ++p) {
    int idx = tid + p * 256;          // 0..511 over 64 rows x 8 f16x8
    int row = idx >> 3, c8 = idx & 7;
    *(f16x8*)&out[(size_t)(n0 + row) * HID + k0 + c8 * 8] = *(const f16x8*)&t[row][c8 * 8];
  }
}

// ---------------- fused f16-MFMA GEMM for all 5 projections (z selects)
// C[M,1024] = f16((A @ W + bias) * scale); A,Wt pre-converted f16; Wt rows = W cols.
// 128x128 tile, BK=32, 4 waves (2x2), each wave 64x64 via 4x4 16x16x32 MFMAs.
__global__ __launch_bounds__(256)
void gemm_all(const _Float16* __restrict__ A16, const _Float16* __restrict__ R16,
              const _Float16* __restrict__ Wt,
              const float* __restrict__ bq, const float* __restrict__ bk,
              const float* __restrict__ bv, const float* __restrict__ bpq,
              _Float16* __restrict__ qo, _Float16* __restrict__ ko,
              _Float16* __restrict__ vo, _Float16* __restrict__ pko,
              _Float16* __restrict__ pqo, float qscale, float pqscale) {
  const int z = blockIdx.z;
  if (z >= 3 && blockIdx.y >= 8) return;          // pos GEMMs: M=1024 only
  const _Float16* A = (z < 3) ? A16 : R16;
  const _Float16* B = Wt + (size_t)z * HID * HID;
  const float* bias = z == 0 ? bq : z == 1 ? bk : z == 2 ? bv : z == 3 ? (const float*)nullptr : bpq;
  _Float16* C = z == 0 ? qo : z == 1 ? ko : z == 2 ? vo : z == 3 ? pko : pqo;
  const float scale = z == 0 ? qscale : z == 4 ? pqscale : 1.0f;

  __shared__ _Float16 As[128 * 40];
  __shared__ _Float16 Bs[128 * 40];
  const int tid = threadIdx.x;
  const int m0 = blockIdx.y * 128, n0 = blockIdx.x * 128;
  const int w = tid >> 6, l = tid & 63;
  const int wr = w >> 1, wc = w & 1;
  const int lr = l & 15, lh = l >> 4;

  f32x4 acc[4][4];
  #pragma unroll
  for (int m = 0; m < 4; ++m)
    #pragma unroll
    for (int n = 0; n < 4; ++n)
      acc[m][n] = (f32x4){0.f, 0.f, 0.f, 0.f};

  for (int k0 = 0; k0 < HID; k0 += 32) {
    __syncthreads();
    // 128 rows x 32 k = 512 f16x8 per array; 2 per thread each
    #pragma unroll
    for (int p = 0; p < 2; ++p) {
      int idx = tid + p * 256;
      int row = idx >> 2, c = idx & 3;
      *(f16x8*)&As[row * 40 + c * 8] = *(const f16x8*)&A[(size_t)(m0 + row) * HID + k0 + c * 8];
      *(f16x8*)&Bs[row * 40 + c * 8] = *(const f16x8*)&B[(size_t)(n0 + row) * HID + k0 + c * 8];
    }
    __syncthreads();

    f16x8 af[4], bfr[4];
    #pragma unroll
    for (int m = 0; m < 4; ++m)
      af[m] = *(const f16x8*)&As[(wr * 64 + m * 16 + lr) * 40 + lh * 8];
    #pragma unroll
    for (int n = 0; n < 4; ++n)
      bfr[n] = *(const f16x8*)&Bs[(wc * 64 + n * 16 + lr) * 40 + lh * 8];
    #pragma unroll
    for (int m = 0; m < 4; ++m)
      #pragma unroll
      for (int n = 0; n < 4; ++n)
        acc[m][n] = __builtin_amdgcn_mfma_f32_16x16x32_f16(af[m], bfr[n], acc[m][n], 0, 0, 0);
  }

  #pragma unroll
  for (int n = 0; n < 4; ++n) {
    int col = n0 + wc * 64 + n * 16 + lr;
    float bv_ = bias ? bias[col] : 0.0f;
    #pragma unroll
    for (int m = 0; m < 4; ++m)
      #pragma unroll
      for (int r = 0; r < 4; ++r) {
        int row = m0 + wr * 64 + m * 16 + lh * 4 + r;
        C[(size_t)row * HID + col] = (_Float16)((acc[m][n][r] + bv_) * scale);
      }
  }
}

// ---------------- fused disentangled attention, f16 MFMA, fp32 softmax
// scores[q,k] = q.k + q.pos_k[rr] + k.pos_q[rr],  rr = clip(q-k+512, 0, 1023)
// (q pre-scaled 1/8; pos_q pre-scaled 1/(8*sqrt(192)))
// 4 waves, each owns 16 q-rows and the FULL 64-col score row.
__global__ __launch_bounds__(256, 2)
void attn_mfma(const _Float16* __restrict__ qg, const _Float16* __restrict__ kg,
               const _Float16* __restrict__ vg, const _Float16* __restrict__ pkg,
               const _Float16* __restrict__ pqg, float* __restrict__ outg) {
  const int q0 = blockIdx.x * 64;
  const int h = blockIdx.y, b = blockIdx.z;
  const int tid = threadIdx.x;
  const int w = tid >> 6, l = tid & 63;
  const int lr = l & 15, lh = l >> 4;
  const size_t hoff = (size_t)h * DH;

  __shared__ _Float16 qs[64 * PSTR];
  __shared__ _Float16 ks[64 * PSTR];
  __shared__ _Float16 vst[64 * PSTR];   // V^T: vst[d][ki]
  __shared__ _Float16 ps[64 * PSTR];    // P tile (qi-major)
  __shared__ _Float16 posA[128 * PSTR]; // pos_k rows; aliased by c2pT[ri][qi]
  __shared__ _Float16 posB[128 * PSTR]; // pos_q rows; aliased by p2cT[ri][ki]
  _Float16* c2pT = posA;
  _Float16* p2cT = posB;

  // stage Q once (first loop-top sync covers it)
  for (int idx = tid; idx < 64 * 8; idx += 256) {
    int row = idx >> 3, c = idx & 7;
    *(f16x8*)&qs[row * PSTR + c * 8] =
        *(const f16x8*)&qg[((size_t)(b * SEQ + q0 + row)) * HID + hoff + c * 8];
  }

  f32x4 accO[4];
  float m_[4], l_[4];
  #pragma unroll
  for (int r = 0; r < 4; ++r) { m_[r] = -1e30f; l_[r] = 0.0f; }
  #pragma unroll
  for (int nt = 0; nt < 4; ++nt) accO[nt] = (f32x4){0.f, 0.f, 0.f, 0.f};

  for (int k0 = 0; k0 < SEQ; k0 += 64) {
    __syncthreads();
    // ---- stage K, V^T, pos rows ----
    for (int idx = tid; idx < 64 * 8; idx += 256) {
      int row = idx >> 3, c = idx & 7;
      *(f16x8*)&ks[row * PSTR + c * 8] =
          *(const f16x8*)&kg[((size_t)(b * SEQ + k0 + row)) * HID + hoff + c * 8];
    }
    for (int idx = tid; idx < 64 * 8; idx += 256) {
      int row = idx >> 3, c = idx & 7;
      f16x8 vv = *(const f16x8*)&vg[((size_t)(b * SEQ + k0 + row)) * HID + hoff + c * 8];
      #pragma unroll
      for (int jj = 0; jj < 8; ++jj) {
        int j = (jj + c) & 7;                      // rotated order (bank spread)
        vst[(c * 8 + j) * PSTR + row] = vv[j];     // vst[d][ki] = V[ki][d]
      }
    }
    const int r_lo = min(max(q0 - k0 - 63 + SPAN, 0), 2 * SPAN - 1);
    const int r_hi = min(max(q0 - k0 + 63 + SPAN, 0), 2 * SPAN - 1);
    const int nr = r_hi - r_lo + 1;
    const int bt_lim = (nr + 15) >> 4;             // band tiles actually needed
    for (int idx = tid; idx < nr * 8; idx += 256) {
      int row = idx >> 3, c = idx & 7;
      size_t gb = ((size_t)(r_lo + row)) * HID + hoff + c * 8;
      *(f16x8*)&posA[row * PSTR + c * 8] = *(const f16x8*)&pkg[gb];
      *(f16x8*)&posB[row * PSTR + c * 8] = *(const f16x8*)&pqg[gb];
    }
    __syncthreads();

    // ---- MFMA phase ----
    f16x8 aq[2], ak[2];
    #pragma unroll
    for (int kk = 0; kk < 2; ++kk) {
      aq[kk] = *(const f16x8*)&qs[(w * 16 + lr) * PSTR + kk * 32 + lh * 8];
      ak[kk] = *(const f16x8*)&ks[(w * 16 + lr) * PSTR + kk * 32 + lh * 8];
    }

    // QK^T: full 64 cols for this wave's 16 q-rows
    f32x4 sqk[4];
    #pragma unroll
    for (int nt = 0; nt < 4; ++nt) sqk[nt] = (f32x4){0.f, 0.f, 0.f, 0.f};
    #pragma unroll
    for (int nt = 0; nt < 4; ++nt)
      #pragma unroll
      for (int kk = 0; kk < 2; ++kk) {
        f16x8 bk = *(const f16x8*)&ks[(nt * 16 + lr) * PSTR + kk * 32 + lh * 8];
        sqk[nt] = __builtin_amdgcn_mfma_f32_16x16x32_f16(aq[kk], bk, sqk[nt], 0, 0, 0);
      }

    // c2p / p2c bands: [16 rows][bt_lim*16 r-cols] (clipped tiles skipped)
    f32x4 bandA[8], bandB[8];
    #pragma unroll
    for (int bt = 0; bt < 8; ++bt) {
      bandA[bt] = (f32x4){0.f, 0.f, 0.f, 0.f};
      bandB[bt] = (f32x4){0.f, 0.f, 0.f, 0.f};
    }
    #pragma unroll
    for (int bt = 0; bt < 8; ++bt)
      if (bt < bt_lim)
        #pragma unroll
        for (int kk = 0; kk < 2; ++kk) {
          f16x8 bp = *(const f16x8*)&posA[(bt * 16 + lr) * PSTR + kk * 32 + lh * 8];
          bandA[bt] = __builtin_amdgcn_mfma_f32_16x16x32_f16(aq[kk], bp, bandA[bt], 0, 0, 0);
        }
    #pragma unroll
    for (int bt = 0; bt < 8; ++bt)
      if (bt < bt_lim)
        #pragma unroll
        for (int kk = 0; kk < 2; ++kk) {
          f16x8 bp = *(const f16x8*)&posB[(bt * 16 + lr) * PSTR + kk * 32 + lh * 8];
          bandB[bt] = __builtin_amdgcn_mfma_f32_16x16x32_f16(ak[kk], bp, bandB[bt], 0, 0, 0);
        }
    __syncthreads();  // all reads of posA/posB complete

    // ---- write bands TRANSPOSED into pos LDS space (f16x4 vector writes) ----
    #pragma unroll
    for (int bt = 0; bt < 8; ++bt)
      if (bt < bt_lim) {
        f16x4 wa, wb;
        #pragma unroll
        for (int r = 0; r < 4; ++r) {
          wa[r] = (_Float16)bandA[bt][r];
          wb[r] = (_Float16)bandB[bt][r];
        }
        *(f16x4*)&c2pT[(bt * 16 + lr) * PSTR + w * 16 + lh * 4] = wa;
        *(f16x4*)&p2cT[(bt * 16 + lr) * PSTR + w * 16 + lh * 4] = wb;
      }
    __syncthreads();

    // ---- assemble scores, online softmax (full row per wave), write P ----
    const int rfix = (q0 - k0 + SPAN) - r_lo;
    #pragma unroll
    for (int r = 0; r < 4; ++r) {
      int qi = w * 16 + lh * 4 + r;
      float sc[4];
      if (nr == 1) {
        // fully clipped tile: c2p const per qi, p2c const per ki
        float cA = (float)c2pT[qi];
        #pragma unroll
        for (int nt = 0; nt < 4; ++nt)
          sc[nt] = sqk[nt][r] + cA + (float)p2cT[nt * 16 + lr];
      } else {
        #pragma unroll
        for (int nt = 0; nt < 4; ++nt) {
          int ki = nt * 16 + lr;
          int ri = min(max(rfix + qi - ki, 0), nr - 1);
          sc[nt] = sqk[nt][r] + (float)c2pT[ri * PSTR + qi] + (float)p2cT[ri * PSTR + ki];
        }
      }
      float mx = fmaxf(fmaxf(sc[0], sc[1]), fmaxf(sc[2], sc[3]));
      #pragma unroll
      for (int off = 1; off < 16; off <<= 1)
        mx = fmaxf(mx, __shfl_xor(mx, off, 64));
      float mnew = fmaxf(m_[r], mx);
      float alpha = __expf(m_[r] - mnew);
      float s0 = 0.0f;
      #pragma unroll
      for (int nt = 0; nt < 4; ++nt) {
        float p = __expf(sc[nt] - mnew);
        s0 += p;
        ps[qi * PSTR + nt * 16 + lr] = (_Float16)p;
      }
      #pragma unroll
      for (int off = 1; off < 16; off <<= 1)
        s0 += __shfl_xor(s0, off, 64);
      l_[r] = l_[r] * alpha + s0;
      m_[r] = mnew;
      #pragma unroll
      for (int nt = 0; nt < 4; ++nt) accO[nt][r] *= alpha;
    }
    __syncthreads();

    // ---- PV: O[16 q-rows][64 d] += P[16][64] @ V[64][64] ----
    f16x8 pa[2];
    #pragma unroll
    for (int kk = 0; kk < 2; ++kk)
      pa[kk] = *(const f16x8*)&ps[(w * 16 + lr) * PSTR + kk * 32 + lh * 8];
    #pragma unroll
    for (int nt = 0; nt < 4; ++nt)
      #pragma unroll
      for (int kk = 0; kk < 2; ++kk) {
        f16x8 vb = *(const f16x8*)&vst[(nt * 16 + lr) * PSTR + kk * 32 + lh * 8];
        accO[nt] = __builtin_amdgcn_mfma_f32_16x16x32_f16(pa[kk], vb, accO[nt], 0, 0, 0);
      }
  }

  // ---- output ----
  #pragma unroll
  for (int r = 0; r < 4; ++r) {
    float inv = 1.0f / l_[r];
    int row = q0 + w * 16 + lh * 4 + r;
    #pragma unroll
    for (int nt = 0; nt < 4; ++nt) {
      int col = h * DH + nt * 16 + lr;
      outg[((size_t)(b * SEQ + row)) * HID + col] = accO[nt][r] * inv;
    }
  }
}

extern "C" void kernel_launch(void* const* d_in, const int* in_sizes, int n_in,
                              void* d_out, int out_size, void* d_ws, size_t ws_size,
                              hipStream_t stream) {
  const float* hs  = (const float*)d_in[0];
  const float* rel = (const float*)d_in[1];
  const float* Wq  = (const float*)d_in[2];
  const float* bq  = (const float*)d_in[3];
  const float* Wk  = (const float*)d_in[4];
  const float* bk  = (const float*)d_in[5];
  const float* Wv  = (const float*)d_in[6];
  const float* bv  = (const float*)d_in[7];
  const float* Wpk = (const float*)d_in[8];
  const float* Wpq = (const float*)d_in[9];
  const float* bpq = (const float*)d_in[10];
  float* out = (float*)d_out;

  _Float16* ws = (_Float16*)d_ws;
  _Float16* q   = ws;                         // 4096x1024 f16
  _Float16* k   = ws + 4194304;
  _Float16* v   = ws + 8388608;
  _Float16* pk  = ws + 12582912;              // 1024x1024 f16
  _Float16* pq  = ws + 13631488;
  _Float16* A16 = ws + 14680064;              // hs f16 (4096x1024)
  _Float16* R16 = ws + 18874368;              // rel f16 (1024x1024)
  _Float16* Wt  = ws + 19922944;              // 5x 1024x1024 f16 (transposed W)

  const float qscale  = 0.125f;                          // 1/sqrt(64)
  const float pqscale = 1.0f / (8.0f * sqrtf(192.0f));   // 1/(sqrt(64)*sqrt(64*3))

  dim3 blk(256);
  // prep: converts + W transposes
  cvt16<<<dim3(2048), blk, 0, stream>>>(hs, A16, (NB * SEQ * HID) / 4);
  cvt16<<<dim3(1024), blk, 0, stream>>>(rel, R16, (2 * SPAN * HID) / 4);
  transW<<<dim3(16, 16, 5), blk, 0, stream>>>(Wq, Wk, Wv, Wpk, Wpq, Wt);

  // all 5 projection GEMMs in one launch
  gemm_all<<<dim3(HID / 128, (NB * SEQ) / 128, 5), blk, 0, stream>>>(
      A16, R16, Wt, bq, bk, bv, bpq, q, k, v, pk, pq, qscale, pqscale);

  dim3 ga(SEQ / 64, NH, NB);
  attn_mfma<<<ga, blk, 0, stream>>>(q, k, v, pk, pq, out);
}

// Round 8
// 379.838 us; speedup vs baseline: 5.6110x; 1.1738x over previous
//
#include <hip/hip_runtime.h>
#include <math.h>

#define HID 1024
#define NH 16
#define DH 64
#define SEQ 2048
#define NB 2
#define SPAN 512
#define PSTR 72    // padded f16 row stride (144 B: stride-144 b128 frag reads <=2-way)
#define VSTR 66    // vst stride: 33-dword lane stride -> conflict-free b128 reads

typedef __attribute__((ext_vector_type(8))) _Float16 f16x8;
typedef __attribute__((ext_vector_type(4))) _Float16 f16x4;
typedef __attribute__((ext_vector_type(4))) float f32x4;

// xor-butterfly lane swizzle (within 16-lane groups), LDS pipe, 1 instr
#define SWZX(x, imm) __builtin_bit_cast(float, __builtin_amdgcn_ds_swizzle(__builtin_bit_cast(int, (x)), (imm)))

// ---------------- f32 -> f16 convert (n4 = n/4)
__global__ __launch_bounds__(256)
void cvt16(const float* __restrict__ src, _Float16* __restrict__ dst, int n4) {
  int i = blockIdx.x * 256 + threadIdx.x;
  const int stride = gridDim.x * 256;
  for (; i < n4; i += stride) {
    float4 v = ((const float4*)src)[i];
    f16x4 o;
    o.x = (_Float16)v.x; o.y = (_Float16)v.y;
    o.z = (_Float16)v.z; o.w = (_Float16)v.w;
    ((f16x4*)dst)[i] = o;
  }
}

// ---------------- transpose+convert: Wt[z][n][k] = (f16) W_z[k][n]
__global__ __launch_bounds__(256)
void transW(const float* __restrict__ W0, const float* __restrict__ W1,
            const float* __restrict__ W2, const float* __restrict__ W3,
            const float* __restrict__ W4, _Float16* __restrict__ Wt) {
  const int z = blockIdx.z;
  const float* W = z == 0 ? W0 : z == 1 ? W1 : z == 2 ? W2 : z == 3 ? W3 : W4;
  _Float16* out = Wt + (size_t)z * HID * HID;
  const int k0 = blockIdx.x * 64, n0 = blockIdx.y * 64;
  __shared__ _Float16 t[64][72];
  const int tid = threadIdx.x;
  #pragma unroll
  for (int p = 0; p < 4; ++p) {
    int idx = tid + p * 256;          // 0..1023 over 64 rows x 16 float4
    int row = idx >> 4, c4 = idx & 15;
    float4 v = *(const float4*)&W[(size_t)(k0 + row) * HID + n0 + c4 * 4];
    t[c4 * 4 + 0][row] = (_Float16)v.x;
    t[c4 * 4 + 1][row] = (_Float16)v.y;
    t[c4 * 4 + 2][row] = (_Float16)v.z;
    t[c4 * 4 + 3][row] = (_Float16)v.w;
  }
  __syncthreads();
  #pragma unroll
  for (int p = 0; p < 2; ++p) {
    int idx = tid + p * 256;          // 0..511 over 64 rows x 8 f16x8
    int row = idx >> 3, c8 = idx & 7;
    *(f16x8*)&out[(size_t)(n0 + row) * HID + k0 + c8 * 8] = *(const f16x8*)&t[row][c8 * 8];
  }
}

// ---------------- fused f16-MFMA GEMM for all 5 projections (z selects)
__global__ __launch_bounds__(256)
void gemm_all(const _Float16* __restrict__ A16, const _Float16* __restrict__ R16,
              const _Float16* __restrict__ Wt,
              const float* __restrict__ bq, const float* __restrict__ bk,
              const float* __restrict__ bv, const float* __restrict__ bpq,
              _Float16* __restrict__ qo, _Float16* __restrict__ ko,
              _Float16* __restrict__ vo, _Float16* __restrict__ pko,
              _Float16* __restrict__ pqo, float qscale, float pqscale) {
  const int z = blockIdx.z;
  if (z >= 3 && blockIdx.y >= 8) return;          // pos GEMMs: M=1024 only
  const _Float16* A = (z < 3) ? A16 : R16;
  const _Float16* B = Wt + (size_t)z * HID * HID;
  const float* bias = z == 0 ? bq : z == 1 ? bk : z == 2 ? bv : z == 3 ? (const float*)nullptr : bpq;
  _Float16* C = z == 0 ? qo : z == 1 ? ko : z == 2 ? vo : z == 3 ? pko : pqo;
  const float scale = z == 0 ? qscale : z == 4 ? pqscale : 1.0f;

  __shared__ _Float16 As[128 * 40];
  __shared__ _Float16 Bs[128 * 40];
  const int tid = threadIdx.x;
  const int m0 = blockIdx.y * 128, n0 = blockIdx.x * 128;
  const int w = tid >> 6, l = tid & 63;
  const int wr = w >> 1, wc = w & 1;
  const int lr = l & 15, lh = l >> 4;

  f32x4 acc[4][4];
  #pragma unroll
  for (int m = 0; m < 4; ++m)
    #pragma unroll
    for (int n = 0; n < 4; ++n)
      acc[m][n] = (f32x4){0.f, 0.f, 0.f, 0.f};

  for (int k0 = 0; k0 < HID; k0 += 32) {
    __syncthreads();
    #pragma unroll
    for (int p = 0; p < 2; ++p) {
      int idx = tid + p * 256;
      int row = idx >> 2, c = idx & 3;
      *(f16x8*)&As[row * 40 + c * 8] = *(const f16x8*)&A[(size_t)(m0 + row) * HID + k0 + c * 8];
      *(f16x8*)&Bs[row * 40 + c * 8] = *(const f16x8*)&B[(size_t)(n0 + row) * HID + k0 + c * 8];
    }
    __syncthreads();

    f16x8 af[4], bfr[4];
    #pragma unroll
    for (int m = 0; m < 4; ++m)
      af[m] = *(const f16x8*)&As[(wr * 64 + m * 16 + lr) * 40 + lh * 8];
    #pragma unroll
    for (int n = 0; n < 4; ++n)
      bfr[n] = *(const f16x8*)&Bs[(wc * 64 + n * 16 + lr) * 40 + lh * 8];
    #pragma unroll
    for (int m = 0; m < 4; ++m)
      #pragma unroll
      for (int n = 0; n < 4; ++n)
        acc[m][n] = __builtin_amdgcn_mfma_f32_16x16x32_f16(af[m], bfr[n], acc[m][n], 0, 0, 0);
  }

  #pragma unroll
  for (int n = 0; n < 4; ++n) {
    int col = n0 + wc * 64 + n * 16 + lr;
    float bv_ = bias ? bias[col] : 0.0f;
    #pragma unroll
    for (int m = 0; m < 4; ++m)
      #pragma unroll
      for (int r = 0; r < 4; ++r) {
        int row = m0 + wr * 64 + m * 16 + lh * 4 + r;
        C[(size_t)row * HID + col] = (_Float16)((acc[m][n][r] + bv_) * scale);
      }
  }
}

// ---------------- fused disentangled attention, f16 MFMA, fp32 softmax
// scores[q,k] = q.k + q.pos_k[rr] + k.pos_q[rr],  rr = clip(q-k+512, 0, 1023)
// 4 waves, each owns 16 q-rows and the FULL 64-col score row.
__global__ __launch_bounds__(256, 2)
void attn_mfma(const _Float16* __restrict__ qg, const _Float16* __restrict__ kg,
               const _Float16* __restrict__ vg, const _Float16* __restrict__ pkg,
               const _Float16* __restrict__ pqg, float* __restrict__ outg) {
  const int q0 = blockIdx.x * 64;
  const int h = blockIdx.y, b = blockIdx.z;
  const int tid = threadIdx.x;
  const int w = tid >> 6, l = tid & 63;
  const int lr = l & 15, lh = l >> 4;
  const size_t hoff = (size_t)h * DH;

  __shared__ _Float16 qs[64 * PSTR];
  __shared__ _Float16 ks[64 * PSTR];
  __shared__ _Float16 vst[64 * VSTR];   // V^T: vst[d][ki], stride 66
  __shared__ _Float16 ps[64 * PSTR];    // P tile (qi-major)
  __shared__ _Float16 posA[128 * PSTR]; // pos_k rows; aliased by c2pT[ri][qi]
  __shared__ _Float16 posB[128 * PSTR]; // pos_q rows; aliased by p2cT[ri][ki]
  _Float16* c2pT = posA;
  _Float16* p2cT = posB;

  // stage Q once, hoist Q fragments to registers (loop-invariant)
  for (int idx = tid; idx < 64 * 8; idx += 256) {
    int row = idx >> 3, c = idx & 7;
    *(f16x8*)&qs[row * PSTR + c * 8] =
        *(const f16x8*)&qg[((size_t)(b * SEQ + q0 + row)) * HID + hoff + c * 8];
  }
  __syncthreads();
  f16x8 aq[2];
  #pragma unroll
  for (int kk = 0; kk < 2; ++kk)
    aq[kk] = *(const f16x8*)&qs[(w * 16 + lr) * PSTR + kk * 32 + lh * 8];

  f32x4 accO[4];
  float m_[4], l_[4];
  #pragma unroll
  for (int r = 0; r < 4; ++r) { m_[r] = -1e30f; l_[r] = 0.0f; }  // l_ is PER-LANE partial
  #pragma unroll
  for (int nt = 0; nt < 4; ++nt) accO[nt] = (f32x4){0.f, 0.f, 0.f, 0.f};

  const int vd4 = tid & 15, vkq = tid >> 4;   // V-staging: 4d x 4k block per thread

  for (int k0 = 0; k0 < SEQ; k0 += 64) {
    __syncthreads();
    // ---- stage K ----
    for (int idx = tid; idx < 64 * 8; idx += 256) {
      int row = idx >> 3, c = idx & 7;
      *(f16x8*)&ks[row * PSTR + c * 8] =
          *(const f16x8*)&kg[((size_t)(b * SEQ + k0 + row)) * HID + hoff + c * 8];
    }
    // ---- stage V^T: per-thread 4x4 in-register transpose, b64 writes ----
    {
      f16x4 vr[4];
      #pragma unroll
      for (int j = 0; j < 4; ++j)
        vr[j] = *(const f16x4*)&vg[((size_t)(b * SEQ + k0 + vkq * 4 + j)) * HID + hoff + vd4 * 4];
      #pragma unroll
      for (int di = 0; di < 4; ++di) {
        f16x4 wv;
        wv.x = vr[0][di]; wv.y = vr[1][di]; wv.z = vr[2][di]; wv.w = vr[3][di];
        *(f16x4*)&vst[(vd4 * 4 + di) * VSTR + vkq * 4] = wv;
      }
    }
    const int r_lo = min(max(q0 - k0 - 63 + SPAN, 0), 2 * SPAN - 1);
    const int r_hi = min(max(q0 - k0 + 63 + SPAN, 0), 2 * SPAN - 1);
    const int nr = r_hi - r_lo + 1;
    const int bt_lim = (nr + 15) >> 4;             // band tiles actually needed
    for (int idx = tid; idx < nr * 8; idx += 256) {
      int row = idx >> 3, c = idx & 7;
      size_t gb = ((size_t)(r_lo + row)) * HID + hoff + c * 8;
      *(f16x8*)&posA[row * PSTR + c * 8] = *(const f16x8*)&pkg[gb];
      *(f16x8*)&posB[row * PSTR + c * 8] = *(const f16x8*)&pqg[gb];
    }
    __syncthreads();

    // ---- MFMA phase ----
    f16x8 ak[2];
    #pragma unroll
    for (int kk = 0; kk < 2; ++kk)
      ak[kk] = *(const f16x8*)&ks[(w * 16 + lr) * PSTR + kk * 32 + lh * 8];

    // QK^T: full 64 cols for this wave's 16 q-rows
    f32x4 sqk[4];
    #pragma unroll
    for (int nt = 0; nt < 4; ++nt) sqk[nt] = (f32x4){0.f, 0.f, 0.f, 0.f};
    #pragma unroll
    for (int nt = 0; nt < 4; ++nt)
      #pragma unroll
      for (int kk = 0; kk < 2; ++kk) {
        f16x8 bk = *(const f16x8*)&ks[(nt * 16 + lr) * PSTR + kk * 32 + lh * 8];
        sqk[nt] = __builtin_amdgcn_mfma_f32_16x16x32_f16(aq[kk], bk, sqk[nt], 0, 0, 0);
      }

    // c2p / p2c bands: [16 rows][bt_lim*16 r-cols] (clipped tiles skipped)
    f32x4 bandA[8], bandB[8];
    #pragma unroll
    for (int bt = 0; bt < 8; ++bt) {
      bandA[bt] = (f32x4){0.f, 0.f, 0.f, 0.f};
      bandB[bt] = (f32x4){0.f, 0.f, 0.f, 0.f};
    }
    #pragma unroll
    for (int bt = 0; bt < 8; ++bt)
      if (bt < bt_lim)
        #pragma unroll
        for (int kk = 0; kk < 2; ++kk) {
          f16x8 bp = *(const f16x8*)&posA[(bt * 16 + lr) * PSTR + kk * 32 + lh * 8];
          bandA[bt] = __builtin_amdgcn_mfma_f32_16x16x32_f16(aq[kk], bp, bandA[bt], 0, 0, 0);
        }
    #pragma unroll
    for (int bt = 0; bt < 8; ++bt)
      if (bt < bt_lim)
        #pragma unroll
        for (int kk = 0; kk < 2; ++kk) {
          f16x8 bp = *(const f16x8*)&posB[(bt * 16 + lr) * PSTR + kk * 32 + lh * 8];
          bandB[bt] = __builtin_amdgcn_mfma_f32_16x16x32_f16(ak[kk], bp, bandB[bt], 0, 0, 0);
        }
    __syncthreads();  // all reads of posA/posB complete

    // ---- write bands TRANSPOSED into pos LDS space (f16x4 vector writes) ----
    #pragma unroll
    for (int bt = 0; bt < 8; ++bt)
      if (bt < bt_lim) {
        f16x4 wa, wb;
        #pragma unroll
        for (int r = 0; r < 4; ++r) {
          wa[r] = (_Float16)bandA[bt][r];
          wb[r] = (_Float16)bandB[bt][r];
        }
        *(f16x4*)&c2pT[(bt * 16 + lr) * PSTR + w * 16 + lh * 4] = wa;
        *(f16x4*)&p2cT[(bt * 16 + lr) * PSTR + w * 16 + lh * 4] = wb;
      }
    __syncthreads();

    // ---- assemble scores, online softmax (full row per wave), write P ----
    const int rfix = (q0 - k0 + SPAN) - r_lo;
    #pragma unroll
    for (int r = 0; r < 4; ++r) {
      int qi = w * 16 + lh * 4 + r;
      float sc[4];
      if (nr == 1) {
        float cA = (float)c2pT[qi];
        #pragma unroll
        for (int nt = 0; nt < 4; ++nt)
          sc[nt] = sqk[nt][r] + cA + (float)p2cT[nt * 16 + lr];
      } else {
        #pragma unroll
        for (int nt = 0; nt < 4; ++nt) {
          int ki = nt * 16 + lr;
          int ri = min(max(rfix + qi - ki, 0), nr - 1);
          sc[nt] = sqk[nt][r] + (float)c2pT[ri * PSTR + qi] + (float)p2cT[ri * PSTR + ki];
        }
      }
      // row max: 4 ds_swizzle xor-butterfly (within 16 lanes)
      float mx = fmaxf(fmaxf(sc[0], sc[1]), fmaxf(sc[2], sc[3]));
      mx = fmaxf(mx, SWZX(mx, 0x041F));
      mx = fmaxf(mx, SWZX(mx, 0x081F));
      mx = fmaxf(mx, SWZX(mx, 0x101F));
      mx = fmaxf(mx, SWZX(mx, 0x201F));
      float mnew = fmaxf(m_[r], mx);
      float alpha = __expf(m_[r] - mnew);
      float s0 = 0.0f;
      #pragma unroll
      for (int nt = 0; nt < 4; ++nt) {
        float p = __expf(sc[nt] - mnew);
        s0 += p;
        ps[qi * PSTR + nt * 16 + lr] = (_Float16)p;
      }
      l_[r] = l_[r] * alpha + s0;   // per-lane partial sum (reduced at epilogue)
      m_[r] = mnew;
      #pragma unroll
      for (int nt = 0; nt < 4; ++nt) accO[nt][r] *= alpha;
    }
    __syncthreads();

    // ---- PV: O[16 q-rows][64 d] += P[16][64] @ V[64][64] ----
    f16x8 pa[2];
    #pragma unroll
    for (int kk = 0; kk < 2; ++kk)
      pa[kk] = *(const f16x8*)&ps[(w * 16 + lr) * PSTR + kk * 32 + lh * 8];
    #pragma unroll
    for (int nt = 0; nt < 4; ++nt)
      #pragma unroll
      for (int kk = 0; kk < 2; ++kk) {
        f16x8 vb = *(const f16x8*)&vst[(nt * 16 + lr) * VSTR + kk * 32 + lh * 8];
        accO[nt] = __builtin_amdgcn_mfma_f32_16x16x32_f16(pa[kk], vb, accO[nt], 0, 0, 0);
      }
  }

  // ---- output (reduce per-lane partial l across the 16-lane row group) ----
  #pragma unroll
  for (int r = 0; r < 4; ++r) {
    float lt = l_[r];
    lt += SWZX(lt, 0x041F);
    lt += SWZX(lt, 0x081F);
    lt += SWZX(lt, 0x101F);
    lt += SWZX(lt, 0x201F);
    float inv = 1.0f / lt;
    int row = q0 + w * 16 + lh * 4 + r;
    #pragma unroll
    for (int nt = 0; nt < 4; ++nt) {
      int col = h * DH + nt * 16 + lr;
      outg[((size_t)(b * SEQ + row)) * HID + col] = accO[nt][r] * inv;
    }
  }
}

extern "C" void kernel_launch(void* const* d_in, const int* in_sizes, int n_in,
                              void* d_out, int out_size, void* d_ws, size_t ws_size,
                              hipStream_t stream) {
  const float* hs  = (const float*)d_in[0];
  const float* rel = (const float*)d_in[1];
  const float* Wq  = (const float*)d_in[2];
  const float* bq  = (const float*)d_in[3];
  const float* Wk  = (const float*)d_in[4];
  const float* bk  = (const float*)d_in[5];
  const float* Wv  = (const float*)d_in[6];
  const float* bv  = (const float*)d_in[7];
  const float* Wpk = (const float*)d_in[8];
  const float* Wpq = (const float*)d_in[9];
  const float* bpq = (const float*)d_in[10];
  float* out = (float*)d_out;

  _Float16* ws = (_Float16*)d_ws;
  _Float16* q   = ws;                         // 4096x1024 f16
  _Float16* k   = ws + 4194304;
  _Float16* v   = ws + 8388608;
  _Float16* pk  = ws + 12582912;              // 1024x1024 f16
  _Float16* pq  = ws + 13631488;
  _Float16* A16 = ws + 14680064;              // hs f16 (4096x1024)
  _Float16* R16 = ws + 18874368;              // rel f16 (1024x1024)
  _Float16* Wt  = ws + 19922944;              // 5x 1024x1024 f16 (transposed W)

  const float qscale  = 0.125f;                          // 1/sqrt(64)
  const float pqscale = 1.0f / (8.0f * sqrtf(192.0f));   // 1/(sqrt(64)*sqrt(64*3))

  dim3 blk(256);
  cvt16<<<dim3(2048), blk, 0, stream>>>(hs, A16, (NB * SEQ * HID) / 4);
  cvt16<<<dim3(1024), blk, 0, stream>>>(rel, R16, (2 * SPAN * HID) / 4);
  transW<<<dim3(16, 16, 5), blk, 0, stream>>>(Wq, Wk, Wv, Wpk, Wpq, Wt);

  gemm_all<<<dim3(HID / 128, (NB * SEQ) / 128, 5), blk, 0, stream>>>(
      A16, R16, Wt, bq, bk, bv, bpq, q, k, v, pk, pq, qscale, pqscale);

  dim3 ga(SEQ / 64, NH, NB);
  attn_mfma<<<ga, blk, 0, stream>>>(q, k, v, pk, pq, out);
}

// Round 10
// 367.658 us; speedup vs baseline: 5.7969x; 1.0331x over previous
//
#include <hip/hip_runtime.h>
#include <math.h>

#define HID 1024
#define NH 16
#define DH 64
#define SEQ 2048
#define NB 2
#define SPAN 512
#define PSTR 72    // padded f16 row stride for ks/ps/pos (144 B)
#define VSTR 66    // vst stride (132 B)
#define BST  132   // band row stride: 128 ri-cols + pad; lh-step 264 dw = 8 mod 32

typedef __attribute__((ext_vector_type(8))) _Float16 f16x8;
typedef __attribute__((ext_vector_type(4))) _Float16 f16x4;
typedef __attribute__((ext_vector_type(4))) float f32x4;

// DPP ROW_ROR butterfly reduce over 16-lane rows (VALU pipe, no LDS traffic)
__device__ __forceinline__ float dpp_max16(float x) {
  int v;
  v = __builtin_amdgcn_update_dpp(0, __builtin_bit_cast(int, x), 0x128, 0xF, 0xF, true);
  x = fmaxf(x, __builtin_bit_cast(float, v));
  v = __builtin_amdgcn_update_dpp(0, __builtin_bit_cast(int, x), 0x124, 0xF, 0xF, true);
  x = fmaxf(x, __builtin_bit_cast(float, v));
  v = __builtin_amdgcn_update_dpp(0, __builtin_bit_cast(int, x), 0x122, 0xF, 0xF, true);
  x = fmaxf(x, __builtin_bit_cast(float, v));
  v = __builtin_amdgcn_update_dpp(0, __builtin_bit_cast(int, x), 0x121, 0xF, 0xF, true);
  return fmaxf(x, __builtin_bit_cast(float, v));
}
__device__ __forceinline__ float dpp_sum16(float x) {
  int v;
  v = __builtin_amdgcn_update_dpp(0, __builtin_bit_cast(int, x), 0x128, 0xF, 0xF, true);
  x += __builtin_bit_cast(float, v);
  v = __builtin_amdgcn_update_dpp(0, __builtin_bit_cast(int, x), 0x124, 0xF, 0xF, true);
  x += __builtin_bit_cast(float, v);
  v = __builtin_amdgcn_update_dpp(0, __builtin_bit_cast(int, x), 0x122, 0xF, 0xF, true);
  x += __builtin_bit_cast(float, v);
  v = __builtin_amdgcn_update_dpp(0, __builtin_bit_cast(int, x), 0x121, 0xF, 0xF, true);
  return x + __builtin_bit_cast(float, v);
}

// ---------------- f32 -> f16 convert (n4 = n/4)
__global__ __launch_bounds__(256)
void cvt16(const float* __restrict__ src, _Float16* __restrict__ dst, int n4) {
  int i = blockIdx.x * 256 + threadIdx.x;
  const int stride = gridDim.x * 256;
  for (; i < n4; i += stride) {
    float4 v = ((const float4*)src)[i];
    f16x4 o;
    o.x = (_Float16)v.x; o.y = (_Float16)v.y;
    o.z = (_Float16)v.z; o.w = (_Float16)v.w;
    ((f16x4*)dst)[i] = o;
  }
}

// ---------------- transpose+convert: Wt[z][n][k] = (f16) W_z[k][n]
__global__ __launch_bounds__(256)
void transW(const float* __restrict__ W0, const float* __restrict__ W1,
            const float* __restrict__ W2, const float* __restrict__ W3,
            const float* __restrict__ W4, _Float16* __restrict__ Wt) {
  const int z = blockIdx.z;
  const float* W = z == 0 ? W0 : z == 1 ? W1 : z == 2 ? W2 : z == 3 ? W3 : W4;
  _Float16* out = Wt + (size_t)z * HID * HID;
  const int k0 = blockIdx.x * 64, n0 = blockIdx.y * 64;
  __shared__ _Float16 t[64][72];
  const int tid = threadIdx.x;
  #pragma unroll
  for (int p = 0; p < 4; ++p) {
    int idx = tid + p * 256;
    int row = idx >> 4, c4 = idx & 15;
    float4 v = *(const float4*)&W[(size_t)(k0 + row) * HID + n0 + c4 * 4];
    t[c4 * 4 + 0][row] = (_Float16)v.x;
    t[c4 * 4 + 1][row] = (_Float16)v.y;
    t[c4 * 4 + 2][row] = (_Float16)v.z;
    t[c4 * 4 + 3][row] = (_Float16)v.w;
  }
  __syncthreads();
  #pragma unroll
  for (int p = 0; p < 2; ++p) {
    int idx = tid + p * 256;
    int row = idx >> 3, c8 = idx & 7;
    *(f16x8*)&out[(size_t)(n0 + row) * HID + k0 + c8 * 8] = *(const f16x8*)&t[row][c8 * 8];
  }
}

// ---------------- fused f16-MFMA GEMM for all 5 projections (z selects)
__global__ __launch_bounds__(256)
void gemm_all(const _Float16* __restrict__ A16, const _Float16* __restrict__ R16,
              const _Float16* __restrict__ Wt,
              const float* __restrict__ bq, const float* __restrict__ bk,
              const float* __restrict__ bv, const float* __restrict__ bpq,
              _Float16* __restrict__ qo, _Float16* __restrict__ ko,
              _Float16* __restrict__ vo, _Float16* __restrict__ pko,
              _Float16* __restrict__ pqo, float qscale, float pqscale) {
  const int z = blockIdx.z;
  if (z >= 3 && blockIdx.y >= 8) return;          // pos GEMMs: M=1024 only
  const _Float16* A = (z < 3) ? A16 : R16;
  const _Float16* B = Wt + (size_t)z * HID * HID;
  const float* bias = z == 0 ? bq : z == 1 ? bk : z == 2 ? bv : z == 3 ? (const float*)nullptr : bpq;
  _Float16* C = z == 0 ? qo : z == 1 ? ko : z == 2 ? vo : z == 3 ? pko : pqo;
  const float scale = z == 0 ? qscale : z == 4 ? pqscale : 1.0f;

  __shared__ _Float16 As[128 * 40];
  __shared__ _Float16 Bs[128 * 40];
  const int tid = threadIdx.x;
  const int m0 = blockIdx.y * 128, n0 = blockIdx.x * 128;
  const int w = tid >> 6, l = tid & 63;
  const int wr = w >> 1, wc = w & 1;
  const int lr = l & 15, lh = l >> 4;

  f32x4 acc[4][4];
  #pragma unroll
  for (int m = 0; m < 4; ++m)
    #pragma unroll
    for (int n = 0; n < 4; ++n)
      acc[m][n] = (f32x4){0.f, 0.f, 0.f, 0.f};

  for (int k0 = 0; k0 < HID; k0 += 32) {
    __syncthreads();
    #pragma unroll
    for (int p = 0; p < 2; ++p) {
      int idx = tid + p * 256;
      int row = idx >> 2, c = idx & 3;
      *(f16x8*)&As[row * 40 + c * 8] = *(const f16x8*)&A[(size_t)(m0 + row) * HID + k0 + c * 8];
      *(f16x8*)&Bs[row * 40 + c * 8] = *(const f16x8*)&B[(size_t)(n0 + row) * HID + k0 + c * 8];
    }
    __syncthreads();

    f16x8 af[4], bfr[4];
    #pragma unroll
    for (int m = 0; m < 4; ++m)
      af[m] = *(const f16x8*)&As[(wr * 64 + m * 16 + lr) * 40 + lh * 8];
    #pragma unroll
    for (int n = 0; n < 4; ++n)
      bfr[n] = *(const f16x8*)&Bs[(wc * 64 + n * 16 + lr) * 40 + lh * 8];
    #pragma unroll
    for (int m = 0; m < 4; ++m)
      #pragma unroll
      for (int n = 0; n < 4; ++n)
        acc[m][n] = __builtin_amdgcn_mfma_f32_16x16x32_f16(af[m], bfr[n], acc[m][n], 0, 0, 0);
  }

  #pragma unroll
  for (int n = 0; n < 4; ++n) {
    int col = n0 + wc * 64 + n * 16 + lr;
    float bv_ = bias ? bias[col] : 0.0f;
    #pragma unroll
    for (int m = 0; m < 4; ++m)
      #pragma unroll
      for (int r = 0; r < 4; ++r) {
        int row = m0 + wr * 64 + m * 16 + lh * 4 + r;
        C[(size_t)row * HID + col] = (_Float16)((acc[m][n][r] + bv_) * scale);
      }
  }
}

// ---------------- fused disentangled attention, f16 MFMA, fp32 softmax
// scores[q,k] = q.k + q.pos_k[rr] + k.pos_q[rr],  rr = clip(q-k+512, 0, 1023)
// 4 waves, each owns 16 q-rows and the FULL 64-col score row.
__global__ __launch_bounds__(256, 2)
void attn_mfma(const _Float16* __restrict__ qg, const _Float16* __restrict__ kg,
               const _Float16* __restrict__ vg, const _Float16* __restrict__ pkg,
               const _Float16* __restrict__ pqg, float* __restrict__ outg) {
  const int q0 = blockIdx.x * 64;
  const int h = blockIdx.y, b = blockIdx.z;
  const int tid = threadIdx.x;
  const int w = tid >> 6, l = tid & 63;
  const int lr = l & 15, lh = l >> 4;
  const size_t hoff = (size_t)h * DH;

  __shared__ _Float16 ks[64 * PSTR];
  __shared__ _Float16 vst[64 * VSTR];   // V^T: vst[d][ki]
  __shared__ _Float16 ps[64 * PSTR];    // P tile, XOR-swizzled nt-blocks
  __shared__ _Float16 posA[128 * PSTR]; // pos_k rows; aliased by c2pb[row][ri] (BST=132)
  __shared__ _Float16 posB[128 * PSTR]; // pos_q rows; aliased by p2cb[row][ri]
  _Float16* c2pb = posA;                // 64 rows x 132 stride = 8443 < 9216 ok
  _Float16* p2cb = posB;

  // Q fragments straight from global (loop-invariant, no LDS staging)
  f16x8 aq[2];
  #pragma unroll
  for (int kk = 0; kk < 2; ++kk)
    aq[kk] = *(const f16x8*)&qg[((size_t)(b * SEQ + q0 + w * 16 + lr)) * HID + hoff + kk * 32 + lh * 8];

  f32x4 accO[4];
  float m_[4], l_[4];
  #pragma unroll
  for (int r = 0; r < 4; ++r) { m_[r] = -1e30f; l_[r] = 0.0f; }  // l_ per-lane partial
  #pragma unroll
  for (int nt = 0; nt < 4; ++nt) accO[nt] = (f32x4){0.f, 0.f, 0.f, 0.f};

  const int vd4 = tid & 15, vkq = tid >> 4;   // V-staging: 4d x 4k block per thread

  for (int k0 = 0; k0 < SEQ; k0 += 64) {
    __syncthreads();
    // ---- stage K ----
    for (int idx = tid; idx < 64 * 8; idx += 256) {
      int row = idx >> 3, c = idx & 7;
      *(f16x8*)&ks[row * PSTR + c * 8] =
          *(const f16x8*)&kg[((size_t)(b * SEQ + k0 + row)) * HID + hoff + c * 8];
    }
    // ---- stage V^T: per-thread 4x4 in-register transpose, b64 writes ----
    {
      f16x4 vr[4];
      #pragma unroll
      for (int j = 0; j < 4; ++j)
        vr[j] = *(const f16x4*)&vg[((size_t)(b * SEQ + k0 + vkq * 4 + j)) * HID + hoff + vd4 * 4];
      #pragma unroll
      for (int di = 0; di < 4; ++di) {
        f16x4 wv;
        wv.x = vr[0][di]; wv.y = vr[1][di]; wv.z = vr[2][di]; wv.w = vr[3][di];
        *(f16x4*)&vst[(vd4 * 4 + di) * VSTR + vkq * 4] = wv;
      }
    }
    const int r_lo = min(max(q0 - k0 - 63 + SPAN, 0), 2 * SPAN - 1);
    const int r_hi = min(max(q0 - k0 + 63 + SPAN, 0), 2 * SPAN - 1);
    const int nr = r_hi - r_lo + 1;
    const int bt_lim = (nr + 15) >> 4;             // band tiles actually needed
    for (int idx = tid; idx < nr * 8; idx += 256) {
      int row = idx >> 3, c = idx & 7;
      size_t gb = ((size_t)(r_lo + row)) * HID + hoff + c * 8;
      *(f16x8*)&posA[row * PSTR + c * 8] = *(const f16x8*)&pkg[gb];
      *(f16x8*)&posB[row * PSTR + c * 8] = *(const f16x8*)&pqg[gb];
    }
    __syncthreads();

    // ---- MFMA phase ----
    f16x8 ak[2];
    #pragma unroll
    for (int kk = 0; kk < 2; ++kk)
      ak[kk] = *(const f16x8*)&ks[(w * 16 + lr) * PSTR + kk * 32 + lh * 8];

    f32x4 sqk[4];
    #pragma unroll
    for (int nt = 0; nt < 4; ++nt) sqk[nt] = (f32x4){0.f, 0.f, 0.f, 0.f};
    #pragma unroll
    for (int nt = 0; nt < 4; ++nt)
      #pragma unroll
      for (int kk = 0; kk < 2; ++kk) {
        f16x8 bk = *(const f16x8*)&ks[(nt * 16 + lr) * PSTR + kk * 32 + lh * 8];
        sqk[nt] = __builtin_amdgcn_mfma_f32_16x16x32_f16(aq[kk], bk, sqk[nt], 0, 0, 0);
      }

    f32x4 bandA[8], bandB[8];
    #pragma unroll
    for (int bt = 0; bt < 8; ++bt) {
      bandA[bt] = (f32x4){0.f, 0.f, 0.f, 0.f};
      bandB[bt] = (f32x4){0.f, 0.f, 0.f, 0.f};
    }
    #pragma unroll
    for (int bt = 0; bt < 8; ++bt)
      if (bt < bt_lim)
        #pragma unroll
        for (int kk = 0; kk < 2; ++kk) {
          f16x8 bp = *(const f16x8*)&posA[(bt * 16 + lr) * PSTR + kk * 32 + lh * 8];
          bandA[bt] = __builtin_amdgcn_mfma_f32_16x16x32_f16(aq[kk], bp, bandA[bt], 0, 0, 0);
        }
    #pragma unroll
    for (int bt = 0; bt < 8; ++bt)
      if (bt < bt_lim)
        #pragma unroll
        for (int kk = 0; kk < 2; ++kk) {
          f16x8 bp = *(const f16x8*)&posB[(bt * 16 + lr) * PSTR + kk * 32 + lh * 8];
          bandB[bt] = __builtin_amdgcn_mfma_f32_16x16x32_f16(ak[kk], bp, bandB[bt], 0, 0, 0);
        }
    __syncthreads();  // all reads of posA/posB complete

    // ---- write bands ROW-MAJOR [row][ri], stride 132 ----
    #pragma unroll
    for (int bt = 0; bt < 8; ++bt)
      if (bt < bt_lim) {
        #pragma unroll
        for (int r = 0; r < 4; ++r) {
          int rowi = w * 16 + lh * 4 + r;
          c2pb[rowi * BST + bt * 16 + lr] = (_Float16)bandA[bt][r];
          p2cb[rowi * BST + bt * 16 + lr] = (_Float16)bandB[bt][r];
        }
      }
    __syncthreads();

    // ---- assemble scores, online softmax (DPP reduce), write swizzled P ----
    const int rfix = (q0 - k0 + SPAN) - r_lo;
    float pc1[4];
    if (nr == 1) {
      #pragma unroll
      for (int nt = 0; nt < 4; ++nt) pc1[nt] = (float)p2cb[(nt * 16 + lr) * BST];
    }
    #pragma unroll
    for (int r = 0; r < 4; ++r) {
      int qi = w * 16 + lh * 4 + r;
      float sc[4];
      if (nr == 1) {
        float cA = (float)c2pb[qi * BST];
        #pragma unroll
        for (int nt = 0; nt < 4; ++nt)
          sc[nt] = sqk[nt][r] + cA + pc1[nt];
      } else {
        #pragma unroll
        for (int nt = 0; nt < 4; ++nt) {
          int ki = nt * 16 + lr;
          int ri = min(max(rfix + qi - ki, 0), nr - 1);
          sc[nt] = sqk[nt][r] + (float)c2pb[qi * BST + ri] + (float)p2cb[ki * BST + ri];
        }
      }
      float mx = dpp_max16(fmaxf(fmaxf(sc[0], sc[1]), fmaxf(sc[2], sc[3])));
      float mnew = fmaxf(m_[r], mx);
      float alpha = __expf(m_[r] - mnew);
      float s0 = 0.0f;
      #pragma unroll
      for (int nt = 0; nt < 4; ++nt) {
        float p = __expf(sc[nt] - mnew);
        s0 += p;
        ps[qi * PSTR + (nt ^ lh) * 16 + lr] = (_Float16)p;   // XOR-swizzled nt-block
      }
      l_[r] = l_[r] * alpha + s0;
      m_[r] = mnew;
      #pragma unroll
      for (int nt = 0; nt < 4; ++nt) accO[nt][r] *= alpha;
    }
    // NO barrier: ps and pa are wave-local; vst unchanged since stage barrier

    // ---- PV: O[16 q-rows][64 d] += P[16][64] @ V[64][64] ----
    f16x8 pa[2];
    const int keyr = lr >> 2;                    // (row>>2)&3 for row = w*16+lr
    #pragma unroll
    for (int kk = 0; kk < 2; ++kk) {
      int blk = (kk * 2 + (lh >> 1)) ^ keyr;     // swizzled 16-elem block
      pa[kk] = *(const f16x8*)&ps[(w * 16 + lr) * PSTR + blk * 16 + (lh & 1) * 8];
    }
    #pragma unroll
    for (int nt = 0; nt < 4; ++nt)
      #pragma unroll
      for (int kk = 0; kk < 2; ++kk) {
        f16x8 vb = *(const f16x8*)&vst[(nt * 16 + lr) * VSTR + kk * 32 + lh * 8];
        accO[nt] = __builtin_amdgcn_mfma_f32_16x16x32_f16(pa[kk], vb, accO[nt], 0, 0, 0);
      }
  }

  // ---- output (reduce per-lane partial l via DPP) ----
  #pragma unroll
  for (int r = 0; r < 4; ++r) {
    float inv = 1.0f / dpp_sum16(l_[r]);
    int row = q0 + w * 16 + lh * 4 + r;
    #pragma unroll
    for (int nt = 0; nt < 4; ++nt) {
      int col = h * DH + nt * 16 + lr;
      outg[((size_t)(b * SEQ + row)) * HID + col] = accO[nt][r] * inv;
    }
  }
}

extern "C" void kernel_launch(void* const* d_in, const int* in_sizes, int n_in,
                              void* d_out, int out_size, void* d_ws, size_t ws_size,
                              hipStream_t stream) {
  const float* hs  = (const float*)d_in[0];
  const float* rel = (const float*)d_in[1];
  const float* Wq  = (const float*)d_in[2];
  const float* bq  = (const float*)d_in[3];
  const float* Wk  = (const float*)d_in[4];
  const float* bk  = (const float*)d_in[5];
  const float* Wv  = (const float*)d_in[6];
  const float* bv  = (const float*)d_in[7];
  const float* Wpk = (const float*)d_in[8];
  const float* Wpq = (const float*)d_in[9];
  const float* bpq = (const float*)d_in[10];
  float* out = (float*)d_out;

  _Float16* ws = (_Float16*)d_ws;
  _Float16* q   = ws;                         // 4096x1024 f16
  _Float16* k   = ws + 4194304;
  _Float16* v   = ws + 8388608;
  _Float16* pk  = ws + 12582912;              // 1024x1024 f16
  _Float16* pq  = ws + 13631488;
  _Float16* A16 = ws + 14680064;              // hs f16
  _Float16* R16 = ws + 18874368;              // rel f16
  _Float16* Wt  = ws + 19922944;              // 5x 1024x1024 f16 (transposed W)

  const float qscale  = 0.125f;                          // 1/sqrt(64)
  const float pqscale = 1.0f / (8.0f * sqrtf(192.0f));   // 1/(sqrt(64)*sqrt(64*3))

  dim3 blk(256);
  cvt16<<<dim3(2048), blk, 0, stream>>>(hs, A16, (NB * SEQ * HID) / 4);
  cvt16<<<dim3(1024), blk, 0, stream>>>(rel, R16, (2 * SPAN * HID) / 4);
  transW<<<dim3(16, 16, 5), blk, 0, stream>>>(Wq, Wk, Wv, Wpk, Wpq, Wt);

  gemm_all<<<dim3(HID / 128, (NB * SEQ) / 128, 5), blk, 0, stream>>>(
      A16, R16, Wt, bq, bk, bv, bpq, q, k, v, pk, pq, qscale, pqscale);

  dim3 ga(SEQ / 64, NH, NB);
  attn_mfma<<<ga, blk, 0, stream>>>(q, k, v, pk, pq, out);
}